// Round 6
// baseline (1003.590 us; speedup 1.0000x reference)
//
#include <hip/hip_runtime.h>
#include <stdint.h>

// Problem constants
constexpr int Cc   = 256;
constexpr int Kc   = 1024;
constexpr int NLOC = 16 * 56 * 56;      // 50176
constexpr int NB   = 2;
constexpr int NTOT = NB * NLOC;         // 100352
constexpr long long ZQV = (long long)NB * Cc * NLOC;

// main tiling
constexpr int RT  = 256;                // rows per block
constexpr int KS  = 128;                // codes per block (one slice)
constexpr int CB  = 16;                 // c per staged phase
constexpr int NSLICE = Kc / KS;         // 8
constexpr int NRT = NTOT / RT;          // 392
constexpr int RTILES_PER_B = NLOC / RT; // 196 (batch never straddles)
// epilogue
constexpr int EB = 64;
constexpr int EBLKS = NTOT / EB;        // 1568

// f32 square with compiler barrier (numpy rounds x*x before summing;
// blocks -ffp-contract fusion into the following add)
__device__ __forceinline__ float sqf(float x) {
    float s = x * x;
    asm("" : "+v"(s));
    return s;
}

// numpy pairwise sum of squares, n=256: two 128-halves, 8 accumulators
// stride-8, tree combine — exact numpy reduction order.
template <typename Loader>
__device__ __forceinline__ float pw256_sq(Loader ld)
{
    float half[2];
    #pragma unroll
    for (int h = 0; h < 2; ++h) {
        float r[8];
        #pragma unroll
        for (int j = 0; j < 8; ++j) r[j] = sqf(ld(h * 128 + j));
        #pragma unroll
        for (int i = 8; i < 128; i += 8)
            #pragma unroll
            for (int j = 0; j < 8; ++j) r[j] += sqf(ld(h * 128 + i + j));
        half[h] = ((r[0] + r[1]) + (r[2] + r[3])) + ((r[4] + r[5]) + (r[6] + r[7]));
    }
    return half[0] + half[1];
}

__global__ void esq_pw(const float* __restrict__ key, float* __restrict__ esq)
{
    int k = blockIdx.x * 256 + threadIdx.x;
    if (k < Kc) {
        const float* a = key + (size_t)k * Cc;
        esq[k] = pw256_sq([&](int c) { return a[c]; });
    }
}

__global__ void zsq_pw(const float* __restrict__ z, float* __restrict__ zsq)
{
    int p = blockIdx.x * 256 + threadIdx.x;
    int b = p / NLOC, loc = p - b * NLOC;
    const float* a = z + (size_t)b * Cc * NLOC + loc;
    zsq[p] = pw256_sq([&](int c) { return a[(size_t)c * NLOC]; });
}

// granule swizzle for the e-tile (32 granules of 16B per 128-float row)
__device__ __forceinline__ int sgr(int g) { return g ^ (g >> 3); }

// ---------------------------------------------------------------------------
// Main: one block = 256 rows x 128 codes (slice). 16x8 register tile.
// LDS per phase: zt[16][256] linear (16 KB) + et[16][128] swizzled (8 KB).
// Per c-iter per thread: 4 b128 z + 2 b128 e -> 128 fmaf (0.75 B/FMA).
// Candidate = min over codes of packed (f32bits(d)<<32 | k)  == numpy argmin.
// ---------------------------------------------------------------------------
__global__ __launch_bounds__(256, 2)
void vq_main(const float* __restrict__ z, const float* __restrict__ key,
             const float* __restrict__ esq, const float* __restrict__ zsq,
             unsigned long long* __restrict__ cand)
{
    __shared__ __align__(16) char smem[32768];     // zt+et (24.5K) / red (32K)
    float* zt = reinterpret_cast<float*>(smem);            // [CB][256]
    float* et = reinterpret_cast<float*>(smem + 16384);    // [CB][128]

    const int tid   = threadIdx.x;
    const int bid   = blockIdx.x;
    const int rtile = bid >> 3;
    const int slice = bid & 7;
    const int k0    = slice * KS;
    const int b     = (rtile >= RTILES_PER_B) ? 1 : 0;
    const int loc0  = rtile * RT - b * NLOC;
    const float* zb = z + (size_t)b * Cc * NLOC;

    const int cg = tid & 15;       // code group: 8 codes
    const int rg = tid >> 4;       // row group: 16 rows
    const int eg0 = sgr(2 * cg) * 4;        // float offsets in e row
    const int eg1 = sgr(2 * cg + 1) * 4;

    float acc[16][8];
    #pragma unroll
    for (int a = 0; a < 16; ++a)
        #pragma unroll
        for (int q = 0; q < 8; ++q) acc[a][q] = 0.0f;

    for (int cc0 = 0; cc0 < Cc; cc0 += CB) {
        __syncthreads();   // previous phase fully consumed
        if (tid < 128) {
            // e stage: task (kq = 4 codes, cq = 4 c): 4x4 reg transpose,
            // swizzled b128 writes
            const int kq = tid & 31, cq = tid >> 5;
            const float* ks = key + (size_t)(k0 + kq * 4) * Cc + cc0 + cq * 4;
            float4 v0 = *reinterpret_cast<const float4*>(ks);
            float4 v1 = *reinterpret_cast<const float4*>(ks + Cc);
            float4 v2 = *reinterpret_cast<const float4*>(ks + 2 * Cc);
            float4 v3 = *reinterpret_cast<const float4*>(ks + 3 * Cc);
            const int pg4 = sgr(kq) * 4;
            *reinterpret_cast<float4*>(et + (cq * 4 + 0) * 128 + pg4) =
                make_float4(v0.x, v1.x, v2.x, v3.x);
            *reinterpret_cast<float4*>(et + (cq * 4 + 1) * 128 + pg4) =
                make_float4(v0.y, v1.y, v2.y, v3.y);
            *reinterpret_cast<float4*>(et + (cq * 4 + 2) * 128 + pg4) =
                make_float4(v0.z, v1.z, v2.z, v3.z);
            *reinterpret_cast<float4*>(et + (cq * 4 + 3) * 128 + pg4) =
                make_float4(v0.w, v1.w, v2.w, v3.w);
        } else {
            // z stage: thread (c = t2>>3, lane-slot t2&7), 8 granule-steps;
            // per step 8 threads cover 128B contiguous of one c-row.
            const int t2 = tid - 128;
            const int c  = t2 >> 3;
            const float* src = zb + (size_t)(cc0 + c) * NLOC + loc0;
            float* dst = zt + c * 256;
            #pragma unroll
            for (int i = 0; i < 8; ++i) {
                int g = (t2 & 7) + 8 * i;          // granule 0..63
                float4 v = *reinterpret_cast<const float4*>(src + g * 4);
                *reinterpret_cast<float4*>(dst + g * 4) = v;
            }
        }
        __syncthreads();

        #pragma unroll 4
        for (int c = 0; c < CB; ++c) {
            const float* zr = zt + c * 256 + rg * 16;
            const float* er = et + c * 128;
            float4 z0 = *reinterpret_cast<const float4*>(zr);
            float4 z1 = *reinterpret_cast<const float4*>(zr + 4);
            float4 z2 = *reinterpret_cast<const float4*>(zr + 8);
            float4 z3 = *reinterpret_cast<const float4*>(zr + 12);
            float4 e0 = *reinterpret_cast<const float4*>(er + eg0);
            float4 e1 = *reinterpret_cast<const float4*>(er + eg1);
            float za[16] = {z0.x, z0.y, z0.z, z0.w, z1.x, z1.y, z1.z, z1.w,
                            z2.x, z2.y, z2.z, z2.w, z3.x, z3.y, z3.z, z3.w};
            float ea[8]  = {e0.x, e0.y, e0.z, e0.w, e1.x, e1.y, e1.z, e1.w};
            #pragma unroll
            for (int a = 0; a < 16; ++a)
                #pragma unroll
                for (int q = 0; q < 8; ++q)
                    acc[a][q] = fmaf(za[a], ea[q], acc[a][q]);
        }
    }

    // finalize: d = f32(f32(zsq+esq) - 2*m); pack; thread-local min over 8 codes
    __syncthreads();   // done with zt/et; red aliases smem
    unsigned long long* red = reinterpret_cast<unsigned long long*>(smem); // [256][16]

    float e2[8];
    #pragma unroll
    for (int q = 0; q < 8; ++q) e2[q] = esq[k0 + cg * 8 + q];

    #pragma unroll
    for (int a = 0; a < 16; ++a) {
        float zr2 = zsq[rtile * RT + rg * 16 + a];
        unsigned long long best = 0xFFFFFFFFFFFFFFFFull;
        #pragma unroll
        for (int q = 0; q < 8; ++q) {
            float t = zr2 + e2[q];
            float d = fmaf(-2.0f, acc[a][q], t);
            unsigned long long pk =
                ((unsigned long long)__float_as_uint(d) << 32)
                | (unsigned)(k0 + cg * 8 + q);
            if (pk < best) best = pk;
        }
        red[(rg * 16 + a) * 16 + cg] = best;
    }
    __syncthreads();

    // per-row min over 16 code-groups; row = tid
    unsigned long long best = red[tid * 16];
    #pragma unroll
    for (int t = 1; t < 16; ++t) {
        unsigned long long v = red[tid * 16 + t];
        if (v < best) best = v;
    }
    cand[(size_t)slice * NTOT + rtile * RT + tid] = best;
}

// ---------------------------------------------------------------------------
// Epilogue: cross-slice reduce -> idx; gather z_q_value; f64 loss partials.
// ---------------------------------------------------------------------------
__global__ __launch_bounds__(256)
void vq_epi(const float* __restrict__ z, const float* __restrict__ key,
            const float* __restrict__ val,
            const unsigned long long* __restrict__ cand,
            float* __restrict__ out, double* __restrict__ partial)
{
    __shared__ int idx_sh[EB];
    __shared__ double wred[4];
    const int tid  = threadIdx.x;
    const int blk  = blockIdx.x;
    const int p0   = blk * EB;
    const int b    = (p0 >= NLOC) ? 1 : 0;
    const int loc0 = p0 - b * NLOC;
    const float* zb = z + (size_t)b * Cc * NLOC;

    if (tid < EB) {
        int p = p0 + tid;
        unsigned long long best = cand[p];
        #pragma unroll
        for (int s = 1; s < NSLICE; ++s) {
            unsigned long long v = cand[(size_t)s * NTOT + p];
            if (v < best) best = v;   // packed: min == (d, first-k) order
        }
        int k = (int)(best & 0xFFFFFFFFu);
        idx_sh[tid] = k;
        out[ZQV + p] = (float)k;
    }
    __syncthreads();

    double lacc = 0.0;
    for (int i = tid; i < Cc * EB; i += 256) {
        int c = i >> 6, n = i & (EB - 1);
        int id = idx_sh[n];
        out[((size_t)b * Cc + c) * NLOC + loc0 + n] = val[(size_t)id * Cc + c];
        double diff = (double)key[(size_t)id * Cc + c]
                    - (double)zb[(size_t)c * NLOC + loc0 + n];
        lacc = fma(diff, diff, lacc);
    }
    for (int off = 32; off > 0; off >>= 1) lacc += __shfl_down(lacc, off);
    if ((tid & 63) == 0) wred[tid >> 6] = lacc;
    __syncthreads();
    if (tid == 0) partial[blk] = wred[0] + wred[1] + wred[2] + wred[3];
}

__global__ void fin_kernel(const double* __restrict__ partial, float* __restrict__ out_loss)
{
    __shared__ double sh[256];
    double s = 0.0;
    for (int i = threadIdx.x; i < EBLKS; i += 256) s += partial[i];
    sh[threadIdx.x] = s;
    __syncthreads();
    for (int st = 128; st > 0; st >>= 1) {
        if (threadIdx.x < st) sh[threadIdx.x] += sh[threadIdx.x + st];
        __syncthreads();
    }
    if (threadIdx.x == 0)
        out_loss[0] = (float)(1.25 * sh[0] / (double)((long long)NTOT * Cc));
}

// ---------------------------------------------------------------------------
extern "C" void kernel_launch(void* const* d_in, const int* in_sizes, int n_in,
                              void* d_out, int out_size, void* d_ws, size_t ws_size,
                              hipStream_t stream)
{
    const float* z   = (const float*)d_in[0];
    const float* key = (const float*)d_in[1];
    const float* val = (const float*)d_in[2];
    float* out = (float*)d_out;

    unsigned long long* cand = (unsigned long long*)d_ws;       // 8*NTOT u64
    double* partial = (double*)(cand + (size_t)NSLICE * NTOT);  // 1568 f64
    float*  esq     = (float*)(partial + EBLKS);                // 1024 f32
    float*  zsq     = esq + Kc;                                 // 100352 f32

    hipLaunchKernelGGL(esq_pw, dim3((Kc + 255) / 256), dim3(256), 0, stream, key, esq);
    hipLaunchKernelGGL(zsq_pw, dim3(NTOT / 256), dim3(256), 0, stream, z, zsq);
    hipLaunchKernelGGL(vq_main, dim3(NRT * NSLICE), dim3(256), 0, stream,
                       z, key, esq, zsq, cand);
    hipLaunchKernelGGL(vq_epi, dim3(EBLKS), dim3(256), 0, stream,
                       z, key, val, cand, out, partial);
    hipLaunchKernelGGL(fin_kernel, dim3(1), dim3(256), 0, stream, partial, out + ZQV + NTOT);
}

// Round 8
// 980.407 us; speedup vs baseline: 1.0236x; 1.0236x over previous
//
#include <hip/hip_runtime.h>
#include <stdint.h>

constexpr int Cc   = 256;
constexpr int Kc   = 1024;
constexpr int NLOC = 16 * 56 * 56;      // 50176
constexpr int NB   = 2;
constexpr int NTOT = NB * NLOC;         // 100352
constexpr long long ZQV = (long long)NB * Cc * NLOC;  // 25690112

// screen tiling
constexpr int SR  = 128;                // rows per screen block
constexpr int SC  = 128;                // codes per kt tile
constexpr int BK  = 64;                 // bf16 k per staged chunk
constexpr int NKT = Kc / SC;            // 8
constexpr int NCH = 768 / BK;           // 12 (K' = 3 terms x 256)
constexpr int SBLK = NTOT / SR;         // 784

constexpr int   SLOTS = 16;
constexpr float WIN   = 4e-4f;          // >= 4x the ~1e-4 correctness bound

constexpr int EB = 64, EBLKS = NTOT / EB;  // 1568

using bf16x8 = __attribute__((ext_vector_type(8))) short;
using f32x4  = __attribute__((ext_vector_type(4))) float;
typedef unsigned long long u64;
typedef unsigned int       u32;
typedef unsigned short     u16;

// ---------------------------------------------------------------------------
// numerics helpers (numpy-exact pieces, unchanged from the passing kernel)
// ---------------------------------------------------------------------------
__device__ __forceinline__ float sqf(float x) {
    float s = x * x;
    asm("" : "+v"(s));
    return s;
}

template <typename Loader>
__device__ __forceinline__ float pw256_sq(Loader ld)
{
    float half[2];
    #pragma unroll
    for (int h = 0; h < 2; ++h) {
        float r[8];
        #pragma unroll
        for (int j = 0; j < 8; ++j) r[j] = sqf(ld(h * 128 + j));
        #pragma unroll
        for (int i = 8; i < 128; i += 8)
            #pragma unroll
            for (int j = 0; j < 8; ++j) r[j] += sqf(ld(h * 128 + i + j));
        half[h] = ((r[0] + r[1]) + (r[2] + r[3])) + ((r[4] + r[5]) + (r[6] + r[7]));
    }
    return half[0] + half[1];
}

__global__ void esq_pw(const float* __restrict__ key, float* __restrict__ esq)
{
    int k = blockIdx.x * 256 + threadIdx.x;
    if (k < Kc) {
        const float* a = key + (size_t)k * Cc;
        esq[k] = pw256_sq([&](int c) { return a[c]; });
    }
}

__global__ void zsq_pw(const float* __restrict__ z, float* __restrict__ zsq)
{
    int p = blockIdx.x * 256 + threadIdx.x;
    int b = p / NLOC, loc = p - b * NLOC;
    const float* a = z + (size_t)b * Cc * NLOC + loc;
    zsq[p] = pw256_sq([&](int c) { return a[(size_t)c * NLOC]; });
}

// bf16 split helpers (RNE)
__device__ __forceinline__ u16 bf16h(float x) {
    u32 u = __float_as_uint(x);
    return (u16)((u + 0x7FFFu + ((u >> 16) & 1u)) >> 16);
}
__device__ __forceinline__ float bf16f(u16 h) {
    return __uint_as_float(((u32)h) << 16);
}

// ---------------------------------------------------------------------------
// split_e: key [1024][256] f32 -> EH, EL bf16 (same layout)
// ---------------------------------------------------------------------------
__global__ void split_e(const float* __restrict__ key,
                        u16* __restrict__ eh, u16* __restrict__ el)
{
    int i = blockIdx.x * 256 + threadIdx.x;
    if (i < Kc * Cc) {
        float x = key[i];
        u16 h = bf16h(x);
        eh[i] = h;
        el[i] = bf16h(x - bf16f(h));
    }
}

// ---------------------------------------------------------------------------
// split_z: z [B][C][NLOC] f32 -> ZTH, ZTL bf16 [NTOT][C] (transposed rows)
// 64-row x 256-c tile via LDS 4x4 micro-transpose.
// ---------------------------------------------------------------------------
__global__ __launch_bounds__(256, 2)
void split_z(const float* __restrict__ z,
             u16* __restrict__ zth, u16* __restrict__ ztl)
{
    __shared__ float t[64][260];   // [n][c], pad 4 floats
    const int tid = threadIdx.x;
    const int n0  = blockIdx.x * 64;
    const int b   = (n0 >= NLOC) ? 1 : 0;
    const int loc0 = n0 - b * NLOC;
    const float* zb = z + (size_t)b * Cc * NLOC;

    // phase 1: load [c][n] coalesced, 4x4 transpose into [n][c]
    {
        const int n4 = tid & 15;
        #pragma unroll
        for (int it = 0; it < 4; ++it) {
            int c4 = (tid >> 4) + it * 16;      // 0..63
            float4 g0 = *reinterpret_cast<const float4*>(zb + (size_t)(c4 * 4 + 0) * NLOC + loc0 + n4 * 4);
            float4 g1 = *reinterpret_cast<const float4*>(zb + (size_t)(c4 * 4 + 1) * NLOC + loc0 + n4 * 4);
            float4 g2 = *reinterpret_cast<const float4*>(zb + (size_t)(c4 * 4 + 2) * NLOC + loc0 + n4 * 4);
            float4 g3 = *reinterpret_cast<const float4*>(zb + (size_t)(c4 * 4 + 3) * NLOC + loc0 + n4 * 4);
            *reinterpret_cast<float4*>(&t[n4 * 4 + 0][c4 * 4]) = make_float4(g0.x, g1.x, g2.x, g3.x);
            *reinterpret_cast<float4*>(&t[n4 * 4 + 1][c4 * 4]) = make_float4(g0.y, g1.y, g2.y, g3.y);
            *reinterpret_cast<float4*>(&t[n4 * 4 + 2][c4 * 4]) = make_float4(g0.z, g1.z, g2.z, g3.z);
            *reinterpret_cast<float4*>(&t[n4 * 4 + 3][c4 * 4]) = make_float4(g0.w, g1.w, g2.w, g3.w);
        }
    }
    __syncthreads();

    // phase 2: per row, convert 8-c chunks -> bf16 hi/lo, 16B stores
    {
        const int row2 = tid >> 5;          // 0..7
        const int ch   = tid & 31;          // 0..31
        #pragma unroll
        for (int rg = 0; rg < 8; ++rg) {
            int row = rg * 8 + row2;
            float4 f0 = *reinterpret_cast<const float4*>(&t[row][ch * 8]);
            float4 f1 = *reinterpret_cast<const float4*>(&t[row][ch * 8 + 4]);
            float xs[8] = {f0.x, f0.y, f0.z, f0.w, f1.x, f1.y, f1.z, f1.w};
            u32 hp[4], lp[4];
            #pragma unroll
            for (int j = 0; j < 4; ++j) {
                u16 h0 = bf16h(xs[2 * j]);
                u16 h1 = bf16h(xs[2 * j + 1]);
                u16 l0 = bf16h(xs[2 * j]     - bf16f(h0));
                u16 l1 = bf16h(xs[2 * j + 1] - bf16f(h1));
                hp[j] = (u32)h0 | ((u32)h1 << 16);
                lp[j] = (u32)l0 | ((u32)l1 << 16);
            }
            size_t o = ((size_t)(n0 + row)) * Cc + ch * 8;
            *reinterpret_cast<uint4*>(zth + o) = make_uint4(hp[0], hp[1], hp[2], hp[3]);
            *reinterpret_cast<uint4*>(ztl + o) = make_uint4(lp[0], lp[1], lp[2], lp[3]);
        }
    }
}

// ---------------------------------------------------------------------------
// gload16: global -> LDS direct, 16B per lane (dest = uniform base + lane*16)
// ---------------------------------------------------------------------------
__device__ __forceinline__ void gload16(const u16* g, u16* lds)
{
    __builtin_amdgcn_global_load_lds(
        (const __attribute__((address_space(1))) u32*)g,
        (__attribute__((address_space(3))) u32*)lds, 16, 0, 0);
}

// ---------------------------------------------------------------------------
// screen: bf16 MFMA GEMM, m~ = zh.eh + zh.el + zl.eh  (K' = 768)
// 128 rows x 128 codes per kt tile, kt loop x8 in-block.
// Emits all codes with d~ <= sliceMin + WIN per (row, kt-slice).
// ---------------------------------------------------------------------------
__global__ __launch_bounds__(256, 3)
void screen(const u16* __restrict__ zth, const u16* __restrict__ ztl,
            const u16* __restrict__ eh,  const u16* __restrict__ el,
            const float* __restrict__ esq, const float* __restrict__ zsq,
            u64* __restrict__ cand, int* __restrict__ cnt)
{
    __shared__ u16  A_lds[SR * BK];    // 16 KB, [row][64] bf16, chunk-swizzled
    __shared__ u16  B_lds[SC * BK];    // 16 KB, [code][64]
    __shared__ float esq_s[Kc];        // 4 KB
    __shared__ float zsq_s[SR];        // 0.5 KB

    const int tid = threadIdx.x;
    const int r0  = blockIdx.x * SR;
    const int wid = tid >> 6, l = tid & 63;
    const int wr  = wid >> 1, wc = wid & 1;

    for (int i = tid; i < Kc; i += 256) esq_s[i] = esq[i];
    for (int i = tid; i < SR; i += 256) zsq_s[i] = zsq[r0 + i];

    for (int kt = 0; kt < NKT; ++kt) {
        f32x4 acc[4][4];
        #pragma unroll
        for (int i = 0; i < 4; ++i)
            #pragma unroll
            for (int j = 0; j < 4; ++j)
                acc[i][j] = f32x4{0.f, 0.f, 0.f, 0.f};

        const u16* bh = eh + (size_t)(kt * SC) * Cc;
        const u16* bl = el + (size_t)(kt * SC) * Cc;

        for (int s = 0; s < NCH; ++s) {
            const int term = s >> 2, c0 = (s & 3) * BK;
            const u16* asrc = (term < 2) ? zth : ztl;
            const u16* bsrc = (term == 1) ? bl : bh;

            __syncthreads();   // previous chunk fully consumed
            // stage: wave stages 32 rows of A and 32 of B; swizzled source
            // chunk so that logical chunk c sits at phys chunk c^(row&7).
            {
                const int sl = ((l & 7) ^ (l >> 3)) * 8;   // swizzled src (ushorts)
                #pragma unroll
                for (int i = 0; i < 4; ++i) {
                    int rowb = wid * 32 + i * 8;
                    int row  = rowb + (l >> 3);
                    gload16(asrc + (size_t)(r0 + row) * Cc + c0 + sl,
                            A_lds + rowb * BK);
                    gload16(bsrc + (size_t)row * Cc + c0 + sl,
                            B_lds + rowb * BK);
                }
            }
            __syncthreads();   // drains vmcnt

            #pragma unroll
            for (int kk = 0; kk < 2; ++kk) {
                bf16x8 a[4], b[4];
                #pragma unroll
                for (int i = 0; i < 4; ++i) {
                    int row = wr * 64 + i * 16 + (l & 15);
                    int pch = (kk * 4 + (l >> 4)) ^ (l & 7);
                    a[i] = *reinterpret_cast<const bf16x8*>(&A_lds[row * BK + pch * 8]);
                }
                #pragma unroll
                for (int j = 0; j < 4; ++j) {
                    int col = wc * 64 + j * 16 + (l & 15);
                    int pch = (kk * 4 + (l >> 4)) ^ (l & 7);
                    b[j] = *reinterpret_cast<const bf16x8*>(&B_lds[col * BK + pch * 8]);
                }
                #pragma unroll
                for (int i = 0; i < 4; ++i)
                    #pragma unroll
                    for (int j = 0; j < 4; ++j)
                        acc[i][j] = __builtin_amdgcn_mfma_f32_16x16x32_bf16(
                            a[i], b[j], acc[i][j], 0, 0, 0);
            }
        }

        // ---- epilogue for this kt: slice-min per row, emit window set ----
        __syncthreads();                       // all LDS reads of chunks done
        u64* gm = reinterpret_cast<u64*>(A_lds);   // [2 wc][128 rows], 2 KB

        #pragma unroll
        for (int i = 0; i < 4; ++i) {
            #pragma unroll
            for (int r = 0; r < 4; ++r) {
                int rloc = wr * 64 + i * 16 + ((l >> 4) << 2) + r;
                float zq = zsq_s[rloc];
                u64 mn = 0xFFFFFFFFFFFFFFFFull;
                #pragma unroll
                for (int j = 0; j < 4; ++j) {
                    int code = kt * SC + wc * 64 + j * 16 + (l & 15);
                    float t = zq + esq_s[code];
                    float d = fmaf(-2.0f, acc[i][j][r], t);
                    u64 pk = ((u64)__float_as_uint(d) << 32) | (u32)code;
                    if (pk < mn) mn = pk;
                }
                #pragma unroll
                for (int m = 1; m < 16; m <<= 1) {
                    u64 o = __shfl_xor(mn, m, 64);
                    if (o < mn) mn = o;
                }
                if ((l & 15) == 0) gm[wc * 128 + rloc] = mn;
            }
        }
        __syncthreads();

        #pragma unroll
        for (int i = 0; i < 4; ++i) {
            #pragma unroll
            for (int r = 0; r < 4; ++r) {
                int rloc = wr * 64 + i * 16 + ((l >> 4) << 2) + r;
                u64 m0 = gm[rloc], m1 = gm[128 + rloc];
                u64 sm = (m0 < m1) ? m0 : m1;
                float thr = __uint_as_float((u32)(sm >> 32)) + WIN;
                float zq = zsq_s[rloc];
                int rg = r0 + rloc;
                #pragma unroll
                for (int j = 0; j < 4; ++j) {
                    int code = kt * SC + wc * 64 + j * 16 + (l & 15);
                    float t = zq + esq_s[code];
                    float d = fmaf(-2.0f, acc[i][j][r], t);
                    if (d <= thr) {
                        int slot = atomicAdd(&cnt[rg], 1);
                        if (slot < SLOTS)
                            cand[(size_t)rg * SLOTS + slot] =
                                ((u64)__float_as_uint(d) << 32) | (u32)code;
                    }
                }
            }
        }
        // next kt's first __syncthreads separates gm reads from A_lds staging
    }
}

// ---------------------------------------------------------------------------
// finalize: pick np-exact argmin from candidates (rescore ambiguous rows),
// gather z_q_value, write idx, accumulate f64 loss partials.
// ---------------------------------------------------------------------------
__global__ __launch_bounds__(256, 4)
void finalize(const float* __restrict__ z, const float* __restrict__ key,
              const float* __restrict__ val,
              const float* __restrict__ esq, const float* __restrict__ zsq,
              const u64* __restrict__ cand, const int* __restrict__ cnt,
              float* __restrict__ out, double* __restrict__ partial)
{
    __shared__ int idx_sh[EB];
    __shared__ double wred[4];
    const int tid = threadIdx.x, blk = blockIdx.x;
    const int p0  = blk * EB;
    const int b   = (p0 >= NLOC) ? 1 : 0;
    const int loc0 = p0 - b * NLOC;
    const float* zb = z + (size_t)b * Cc * NLOC;

    if (tid < EB) {
        const int p = p0 + tid;
        const int c = cnt[p];
        const int n = (c < SLOTS) ? c : SLOTS;
        u64 best = 0xFFFFFFFFFFFFFFFFull;
        for (int s = 0; s < n; ++s) {
            u64 v = cand[(size_t)p * SLOTS + s];
            if (v < best) best = v;
        }
        int kbest = (int)(u32)best;
        const float db = __uint_as_float((u32)(best >> 32));

        if (c > SLOTS) {
            // overflow fallback: full np-exact scan (astronomically rare)
            u64 bb = 0xFFFFFFFFFFFFFFFFull;
            for (int k = 0; k < Kc; ++k) {
                const float* kr = key + (size_t)k * Cc;
                float m = 0.f;
                for (int cc = 0; cc < Cc; ++cc)
                    m = fmaf(zb[(size_t)cc * NLOC + loc0 + tid], kr[cc], m);
                float t = zsq[p] + esq[k];
                float d = fmaf(-2.0f, m, t);
                u64 pk = ((u64)__float_as_uint(d) << 32) | (u32)k;
                if (pk < bb) bb = pk;
            }
            kbest = (int)(u32)bb;
        } else {
            int namb = 0;
            for (int s = 0; s < n; ++s) {
                float dv = __uint_as_float((u32)(cand[(size_t)p * SLOTS + s] >> 32));
                namb += (dv <= db + WIN) ? 1 : 0;
            }
            if (namb > 1) {
                // np-exact rescore of the windowed candidates
                u64 bb = 0xFFFFFFFFFFFFFFFFull;
                for (int s = 0; s < n; ++s) {
                    u64 v = cand[(size_t)p * SLOTS + s];
                    float dv = __uint_as_float((u32)(v >> 32));
                    if (dv <= db + WIN) {
                        int k = (int)(u32)v;
                        const float* kr = key + (size_t)k * Cc;
                        float m = 0.f;
                        for (int cc = 0; cc < Cc; ++cc)
                            m = fmaf(zb[(size_t)cc * NLOC + loc0 + tid], kr[cc], m);
                        float t = zsq[p] + esq[k];
                        float d = fmaf(-2.0f, m, t);
                        u64 pk = ((u64)__float_as_uint(d) << 32) | (u32)k;
                        if (pk < bb) bb = pk;
                    }
                }
                kbest = (int)(u32)bb;
            }
        }
        idx_sh[tid] = kbest;
        out[ZQV + p] = (float)kbest;
    }
    __syncthreads();

    // gather z_q_value (bit-exact copies) + f64 loss
    double lacc = 0.0;
    for (int i = tid; i < Cc * EB; i += 256) {
        int cc = i >> 6, nn = i & (EB - 1);
        int id = idx_sh[nn];
        out[((size_t)b * Cc + cc) * NLOC + loc0 + nn] = val[(size_t)id * Cc + cc];
        double diff = (double)key[(size_t)id * Cc + cc]
                    - (double)zb[(size_t)cc * NLOC + loc0 + nn];
        lacc = fma(diff, diff, lacc);
    }
    for (int off = 32; off > 0; off >>= 1) lacc += __shfl_down(lacc, off);
    if ((tid & 63) == 0) wred[tid >> 6] = lacc;
    __syncthreads();
    if (tid == 0) partial[blk] = wred[0] + wred[1] + wred[2] + wred[3];
}

__global__ void fin_kernel(const double* __restrict__ partial, float* __restrict__ out_loss)
{
    __shared__ double sh[256];
    double s = 0.0;
    for (int i = threadIdx.x; i < EBLKS; i += 256) s += partial[i];
    sh[threadIdx.x] = s;
    __syncthreads();
    for (int st = 128; st > 0; st >>= 1) {
        if (threadIdx.x < st) sh[threadIdx.x] += sh[threadIdx.x + st];
        __syncthreads();
    }
    if (threadIdx.x == 0)
        out_loss[0] = (float)(1.25 * sh[0] / (double)((long long)NTOT * Cc));
}

// ---------------------------------------------------------------------------
extern "C" void kernel_launch(void* const* d_in, const int* in_sizes, int n_in,
                              void* d_out, int out_size, void* d_ws, size_t ws_size,
                              hipStream_t stream)
{
    const float* z   = (const float*)d_in[0];
    const float* key = (const float*)d_in[1];
    const float* val = (const float*)d_in[2];
    float* out = (float*)d_out;

    // ZH/ZL scratch lives in the z_q_value output region (exact fit, dead
    // before finalize overwrites it).
    u16* zth = (u16*)d_out;
    u16* ztl = zth + (size_t)NTOT * Cc;

    u64*    cand    = (u64*)d_ws;                              // 12.85 MB
    int*    cnt     = (int*)(cand + (size_t)NTOT * SLOTS);     // 401 KB
    double* partial = (double*)(cnt + NTOT);                   // 12.5 KB
    float*  esq     = (float*)(partial + EBLKS);               // 4 KB
    float*  zsq     = esq + Kc;                                // 401 KB
    u16*    eh      = (u16*)(zsq + NTOT);                      // 512 KB
    u16*    el      = eh + Kc * Cc;                            // 512 KB

    hipMemsetAsync(cnt, 0, NTOT * sizeof(int), stream);
    hipLaunchKernelGGL(esq_pw, dim3((Kc + 255) / 256), dim3(256), 0, stream, key, esq);
    hipLaunchKernelGGL(zsq_pw, dim3(NTOT / 256), dim3(256), 0, stream, z, zsq);
    hipLaunchKernelGGL(split_e, dim3((Kc * Cc + 255) / 256), dim3(256), 0, stream, key, eh, el);
    hipLaunchKernelGGL(split_z, dim3(NTOT / 64), dim3(256), 0, stream, z, zth, ztl);
    hipLaunchKernelGGL(screen, dim3(SBLK), dim3(256), 0, stream,
                       zth, ztl, eh, el, esq, zsq, cand, cnt);
    hipLaunchKernelGGL(finalize, dim3(EBLKS), dim3(256), 0, stream,
                       z, key, val, esq, zsq, cand, cnt, out, partial);
    hipLaunchKernelGGL(fin_kernel, dim3(1), dim3(256), 0, stream, partial, out + ZQV + NTOT);
}

// Round 9
// 871.521 us; speedup vs baseline: 1.1515x; 1.1249x over previous
//
#include <hip/hip_runtime.h>
#include <stdint.h>

constexpr int Cc   = 256;
constexpr int Kc   = 1024;
constexpr int NLOC = 16 * 56 * 56;      // 50176
constexpr int NB   = 2;
constexpr int NTOT = NB * NLOC;         // 100352
constexpr long long ZQV = (long long)NB * Cc * NLOC;  // 25690112

// screen tiling
constexpr int SR   = 128;               // rows per block
constexpr int SC   = 256;               // codes per kt slice
constexpr int BK   = 64;                // f16 K per staged B chunk
constexpr int KF   = 256;               // full K
constexpr int NKT  = Kc / SC;           // 4
constexpr int NCHUNK = NKT * (KF / BK); // 16
constexpr int SBLK = NTOT / SR;         // 784

constexpr int   SLOTS = 16;
constexpr float WIN   = 3e-4f;          // ~25 sigma of f16-screen error
constexpr float NEG2S = -0.001953125f;  // -2/1024 (descale, exact)

constexpr int EB = 64, EBLKS = NTOT / EB;  // 1568

using f16x8 = __attribute__((ext_vector_type(8))) _Float16;
using f32x4 = __attribute__((ext_vector_type(4))) float;
typedef unsigned long long u64;
typedef unsigned int       u32;
typedef unsigned short     u16;

// ---------------------------------------------------------------------------
// numpy-exact helpers (unchanged from passing kernels)
// ---------------------------------------------------------------------------
__device__ __forceinline__ float sqf(float x) {
    float s = x * x;
    asm("" : "+v"(s));
    return s;
}

template <typename Loader>
__device__ __forceinline__ float pw256_sq(Loader ld)
{
    float half[2];
    #pragma unroll
    for (int h = 0; h < 2; ++h) {
        float r[8];
        #pragma unroll
        for (int j = 0; j < 8; ++j) r[j] = sqf(ld(h * 128 + j));
        #pragma unroll
        for (int i = 8; i < 128; i += 8)
            #pragma unroll
            for (int j = 0; j < 8; ++j) r[j] += sqf(ld(h * 128 + i + j));
        half[h] = ((r[0] + r[1]) + (r[2] + r[3])) + ((r[4] + r[5]) + (r[6] + r[7]));
    }
    return half[0] + half[1];
}

__global__ void esq_pw(const float* __restrict__ key, float* __restrict__ esq)
{
    int k = blockIdx.x * 256 + threadIdx.x;
    if (k < Kc) {
        const float* a = key + (size_t)k * Cc;
        esq[k] = pw256_sq([&](int c) { return a[c]; });
    }
}

__global__ void zsq_pw(const float* __restrict__ z, float* __restrict__ zsq)
{
    int p = blockIdx.x * 256 + threadIdx.x;
    int b = p / NLOC, loc = p - b * NLOC;
    const float* a = z + (size_t)b * Cc * NLOC + loc;
    zsq[p] = pw256_sq([&](int c) { return a[(size_t)c * NLOC]; });
}

__device__ __forceinline__ u16 f16b(float x)
{
    _Float16 h = (_Float16)x;   // v_cvt_f16_f32, RNE
    u16 r;
    __builtin_memcpy(&r, &h, 2);
    return r;
}

// split_e: ef16[k][c] = f16(key[k][c] * 1024)   (exact pow-2 scale -> normal f16)
__global__ void split_e(const float* __restrict__ key, u16* __restrict__ ef16)
{
    int i = blockIdx.x * 256 + threadIdx.x;
    if (i < Kc * Cc) ef16[i] = f16b(key[i] * 1024.0f);
}

// split_z: z [B][C][NLOC] f32 -> zf16 [NTOT][C] f16 (transposed rows)
__global__ __launch_bounds__(256, 2)
void split_z(const float* __restrict__ z, u16* __restrict__ zf16)
{
    __shared__ float t[64][260];   // [n][c], pad 4
    const int tid = threadIdx.x;
    const int n0  = blockIdx.x * 64;
    const int b   = (n0 >= NLOC) ? 1 : 0;
    const int loc0 = n0 - b * NLOC;
    const float* zb = z + (size_t)b * Cc * NLOC;

    {
        const int n4 = tid & 15;
        #pragma unroll
        for (int it = 0; it < 4; ++it) {
            int c4 = (tid >> 4) + it * 16;      // 0..63
            float4 g0 = *reinterpret_cast<const float4*>(zb + (size_t)(c4 * 4 + 0) * NLOC + loc0 + n4 * 4);
            float4 g1 = *reinterpret_cast<const float4*>(zb + (size_t)(c4 * 4 + 1) * NLOC + loc0 + n4 * 4);
            float4 g2 = *reinterpret_cast<const float4*>(zb + (size_t)(c4 * 4 + 2) * NLOC + loc0 + n4 * 4);
            float4 g3 = *reinterpret_cast<const float4*>(zb + (size_t)(c4 * 4 + 3) * NLOC + loc0 + n4 * 4);
            *reinterpret_cast<float4*>(&t[n4 * 4 + 0][c4 * 4]) = make_float4(g0.x, g1.x, g2.x, g3.x);
            *reinterpret_cast<float4*>(&t[n4 * 4 + 1][c4 * 4]) = make_float4(g0.y, g1.y, g2.y, g3.y);
            *reinterpret_cast<float4*>(&t[n4 * 4 + 2][c4 * 4]) = make_float4(g0.z, g1.z, g2.z, g3.z);
            *reinterpret_cast<float4*>(&t[n4 * 4 + 3][c4 * 4]) = make_float4(g0.w, g1.w, g2.w, g3.w);
        }
    }
    __syncthreads();

    {
        const int row2 = tid >> 5;          // 0..7
        const int ch   = tid & 31;          // 0..31
        #pragma unroll
        for (int rg = 0; rg < 8; ++rg) {
            int row = rg * 8 + row2;
            float4 f0 = *reinterpret_cast<const float4*>(&t[row][ch * 8]);
            float4 f1 = *reinterpret_cast<const float4*>(&t[row][ch * 8 + 4]);
            float xs[8] = {f0.x, f0.y, f0.z, f0.w, f1.x, f1.y, f1.z, f1.w};
            u32 hp[4];
            #pragma unroll
            for (int j = 0; j < 4; ++j)
                hp[j] = (u32)f16b(xs[2 * j]) | ((u32)f16b(xs[2 * j + 1]) << 16);
            *reinterpret_cast<uint4*>(zf16 + ((size_t)(n0 + row)) * Cc + ch * 8) =
                make_uint4(hp[0], hp[1], hp[2], hp[3]);
        }
    }
}

// global -> LDS direct, 16B/lane (dest = uniform base + lane*16)
__device__ __forceinline__ void gload16(const u16* g, u16* lds)
{
    __builtin_amdgcn_global_load_lds(
        (const __attribute__((address_space(1))) u32*)g,
        (__attribute__((address_space(3))) u32*)lds, 16, 0, 0);
}

// ---------------------------------------------------------------------------
// screen: f16 MFMA GEMM (K=256), A persisted in LDS, B double-buffered with
// prefetch (stage chunk c+1 before computing chunk c; 1 barrier per chunk).
// Per kt slice (256 codes): slice-min per row, emit codes within WIN.
// ---------------------------------------------------------------------------
__global__ __launch_bounds__(256, 1)
void screen(const u16* __restrict__ zf16, const u16* __restrict__ ef16,
            const float* __restrict__ esq, const float* __restrict__ zsq,
            u64* __restrict__ cand, int* __restrict__ cnt)
{
    __shared__ u16  A_lds[SR * KF];        // 64 KB, [row][K] swizzled granules
    __shared__ u16  B_lds[2][SC * BK];     // 2 x 32 KB, [code][BK] swizzled
    __shared__ u64  gm[2][SR];             // 2 KB
    __shared__ float esq_s[Kc];            // 4 KB
    __shared__ float zsq_s[SR];

    const int tid = threadIdx.x;
    const int r0  = blockIdx.x * SR;
    const int wid = tid >> 6, l = tid & 63;
    const int wr  = wid >> 1, wc = wid & 1;

    // --- stage A once: 16 gload16/wave, 2 rows (512B each) per instr ---
    #pragma unroll
    for (int t = 0; t < 16; ++t) {
        int rowb = wid * 32 + t * 2;
        int r = rowb + (l >> 5);
        int g = (l & 31) ^ ((r & 7) << 2);      // inverse-swizzled source granule
        gload16(zf16 + (size_t)(r0 + r) * KF + g * 8, A_lds + rowb * KF);
    }

    auto stageB = [&](int buf, int chunk) {
        const int ktc = chunk >> 2, sc = chunk & 3;
        #pragma unroll
        for (int t = 0; t < 8; ++t) {
            int cb = wid * 64 + t * 8;
            int code = cb + (l >> 3);
            int g = (l & 7) ^ (code & 7);
            gload16(ef16 + (size_t)(ktc * SC + code) * KF + sc * BK + g * 8,
                    &B_lds[buf][cb * BK]);
        }
    };
    stageB(0, 0);

    for (int i = tid; i < Kc; i += 256) esq_s[i] = esq[i];
    if (tid < SR) zsq_s[tid] = zsq[r0 + tid];

    f32x4 acc[4][8];
    #pragma unroll
    for (int i = 0; i < 4; ++i)
        #pragma unroll
        for (int j = 0; j < 8; ++j)
            acc[i][j] = f32x4{0.f, 0.f, 0.f, 0.f};

    __syncthreads();   // A + B0 landed (vmcnt drained), esq_s/zsq_s visible

    int cur = 0;
    for (int c = 0; c < NCHUNK; ++c) {
        const int s = c & 3;
        if (c + 1 < NCHUNK) stageB(cur ^ 1, c + 1);   // prefetch next chunk

        #pragma unroll
        for (int kk = 0; kk < 2; ++kk) {
            f16x8 af[4], bf[8];
            #pragma unroll
            for (int i = 0; i < 4; ++i) {
                int row = wr * 64 + i * 16 + (l & 15);
                int G   = s * 8 + kk * 4 + (l >> 4);
                int pg  = G ^ ((row & 7) << 2);
                af[i] = *reinterpret_cast<const f16x8*>(&A_lds[row * KF + pg * 8]);
            }
            #pragma unroll
            for (int j = 0; j < 8; ++j) {
                int col = wc * 128 + j * 16 + (l & 15);
                int pg  = (kk * 4 + (l >> 4)) ^ (col & 7);
                bf[j] = *reinterpret_cast<const f16x8*>(&B_lds[cur][col * BK + pg * 8]);
            }
            #pragma unroll
            for (int i = 0; i < 4; ++i)
                #pragma unroll
                for (int j = 0; j < 8; ++j)
                    acc[i][j] = __builtin_amdgcn_mfma_f32_16x16x32_f16(
                        af[i], bf[j], acc[i][j], 0, 0, 0);
        }

        if (s == 3) {
            // ---- kt epilogue: slice-min per row + window emission ----
            const int ktc = c >> 2;
            #pragma unroll
            for (int i = 0; i < 4; ++i) {
                #pragma unroll
                for (int r = 0; r < 4; ++r) {
                    int rloc = wr * 64 + i * 16 + ((l >> 4) << 2) + r;
                    float zq = zsq_s[rloc];
                    u64 mn = 0xFFFFFFFFFFFFFFFFull;
                    #pragma unroll
                    for (int j = 0; j < 8; ++j) {
                        int code = ktc * SC + wc * 128 + j * 16 + (l & 15);
                        float t = zq + esq_s[code];
                        float d = fmaf(NEG2S, acc[i][j][r], t);
                        u64 pk = ((u64)__float_as_uint(d) << 32) | (u32)code;
                        mn = pk < mn ? pk : mn;
                    }
                    #pragma unroll
                    for (int m = 1; m < 16; m <<= 1) {
                        u64 o = __shfl_xor(mn, m, 64);
                        mn = o < mn ? o : mn;
                    }
                    if ((l & 15) == 0) gm[wc][rloc] = mn;
                }
            }
            __syncthreads();
            #pragma unroll
            for (int i = 0; i < 4; ++i) {
                #pragma unroll
                for (int r = 0; r < 4; ++r) {
                    int rloc = wr * 64 + i * 16 + ((l >> 4) << 2) + r;
                    u64 m0 = gm[0][rloc], m1 = gm[1][rloc];
                    u64 sm = m0 < m1 ? m0 : m1;
                    float thr = __uint_as_float((u32)(sm >> 32)) + WIN;
                    float zq = zsq_s[rloc];
                    int rg = r0 + rloc;
                    #pragma unroll
                    for (int j = 0; j < 8; ++j) {
                        int code = ktc * SC + wc * 128 + j * 16 + (l & 15);
                        float t = zq + esq_s[code];
                        float d = fmaf(NEG2S, acc[i][j][r], t);
                        if (d <= thr) {
                            int slot = atomicAdd(&cnt[rg], 1);
                            if (slot < SLOTS)
                                cand[(size_t)rg * SLOTS + slot] =
                                    ((u64)__float_as_uint(d) << 32) | (u32)code;
                        }
                    }
                }
            }
            #pragma unroll
            for (int i = 0; i < 4; ++i)
                #pragma unroll
                for (int j = 0; j < 8; ++j)
                    acc[i][j] = f32x4{0.f, 0.f, 0.f, 0.f};
        }

        __syncthreads();   // drains prefetch vmcnt; buf swap safe
        cur ^= 1;
    }
}

// ---------------------------------------------------------------------------
// finalize: np-exact argmin from candidates (rescore ambiguous), gather, loss
// ---------------------------------------------------------------------------
__global__ __launch_bounds__(256, 4)
void finalize(const float* __restrict__ z, const float* __restrict__ key,
              const float* __restrict__ val,
              const float* __restrict__ esq, const float* __restrict__ zsq,
              const u64* __restrict__ cand, const int* __restrict__ cnt,
              float* __restrict__ out, double* __restrict__ partial)
{
    __shared__ int idx_sh[EB];
    __shared__ double wred[4];
    const int tid = threadIdx.x, blk = blockIdx.x;
    const int p0  = blk * EB;
    const int b   = (p0 >= NLOC) ? 1 : 0;
    const int loc0 = p0 - b * NLOC;
    const float* zb = z + (size_t)b * Cc * NLOC;

    if (tid < EB) {
        const int p = p0 + tid;
        const int c = cnt[p];
        const int n = (c < SLOTS) ? c : SLOTS;
        u64 best = 0xFFFFFFFFFFFFFFFFull;
        for (int s = 0; s < n; ++s) {
            u64 v = cand[(size_t)p * SLOTS + s];
            if (v < best) best = v;
        }
        int kbest = (int)(u32)best;
        const float db = __uint_as_float((u32)(best >> 32));

        if (c > SLOTS) {
            // overflow backstop: full np-exact scan (data-dependent, ~never)
            u64 bb = 0xFFFFFFFFFFFFFFFFull;
            for (int k = 0; k < Kc; ++k) {
                const float* kr = key + (size_t)k * Cc;
                float m = 0.f;
                for (int cc = 0; cc < Cc; ++cc)
                    m = fmaf(zb[(size_t)cc * NLOC + loc0 + tid], kr[cc], m);
                float t = zsq[p] + esq[k];
                float d = fmaf(-2.0f, m, t);
                u64 pk = ((u64)__float_as_uint(d) << 32) | (u32)k;
                if (pk < bb) bb = pk;
            }
            kbest = (int)(u32)bb;
        } else {
            int namb = 0;
            for (int s = 0; s < n; ++s) {
                float dv = __uint_as_float((u32)(cand[(size_t)p * SLOTS + s] >> 32));
                namb += (dv <= db + WIN) ? 1 : 0;
            }
            if (namb > 1) {
                u64 bb = 0xFFFFFFFFFFFFFFFFull;
                for (int s = 0; s < n; ++s) {
                    u64 v = cand[(size_t)p * SLOTS + s];
                    float dv = __uint_as_float((u32)(v >> 32));
                    if (dv <= db + WIN) {
                        int k = (int)(u32)v;
                        const float* kr = key + (size_t)k * Cc;
                        float m = 0.f;
                        for (int cc = 0; cc < Cc; ++cc)
                            m = fmaf(zb[(size_t)cc * NLOC + loc0 + tid], kr[cc], m);
                        float t = zsq[p] + esq[k];
                        float d = fmaf(-2.0f, m, t);
                        u64 pk = ((u64)__float_as_uint(d) << 32) | (u32)k;
                        if (pk < bb) bb = pk;
                    }
                }
                kbest = (int)(u32)bb;
            }
        }
        idx_sh[tid] = kbest;
        out[ZQV + p] = (float)kbest;
    }
    __syncthreads();

    double lacc = 0.0;
    for (int i = tid; i < Cc * EB; i += 256) {
        int cc = i >> 6, nn = i & (EB - 1);
        int id = idx_sh[nn];
        out[((size_t)b * Cc + cc) * NLOC + loc0 + nn] = val[(size_t)id * Cc + cc];
        double diff = (double)key[(size_t)id * Cc + cc]
                    - (double)zb[(size_t)cc * NLOC + loc0 + nn];
        lacc = fma(diff, diff, lacc);
    }
    for (int off = 32; off > 0; off >>= 1) lacc += __shfl_down(lacc, off);
    if ((tid & 63) == 0) wred[tid >> 6] = lacc;
    __syncthreads();
    if (tid == 0) partial[blk] = wred[0] + wred[1] + wred[2] + wred[3];
}

__global__ void fin_kernel(const double* __restrict__ partial, float* __restrict__ out_loss)
{
    __shared__ double sh[256];
    double s = 0.0;
    for (int i = threadIdx.x; i < EBLKS; i += 256) s += partial[i];
    sh[threadIdx.x] = s;
    __syncthreads();
    for (int st = 128; st > 0; st >>= 1) {
        if (threadIdx.x < st) sh[threadIdx.x] += sh[threadIdx.x + st];
        __syncthreads();
    }
    if (threadIdx.x == 0)
        out_loss[0] = (float)(1.25 * sh[0] / (double)((long long)NTOT * Cc));
}

// ---------------------------------------------------------------------------
extern "C" void kernel_launch(void* const* d_in, const int* in_sizes, int n_in,
                              void* d_out, int out_size, void* d_ws, size_t ws_size,
                              hipStream_t stream)
{
    const float* z   = (const float*)d_in[0];
    const float* key = (const float*)d_in[1];
    const float* val = (const float*)d_in[2];
    float* out = (float*)d_out;

    // zf16 scratch lives in the z_q_value output region (dead before finalize)
    u16* zf16 = (u16*)d_out;

    u16*    ef16    = (u16*)d_ws;                              // 512 KB
    u64*    cand    = (u64*)(ef16 + (size_t)Kc * Cc);          // 12.85 MB
    int*    cnt     = (int*)(cand + (size_t)NTOT * SLOTS);     // 401 KB
    double* partial = (double*)(cnt + NTOT);                   // 12.5 KB
    float*  esq     = (float*)(partial + EBLKS);               // 4 KB
    float*  zsq     = esq + Kc;                                // 401 KB

    hipMemsetAsync(cnt, 0, NTOT * sizeof(int), stream);
    hipLaunchKernelGGL(esq_pw, dim3((Kc + 255) / 256), dim3(256), 0, stream, key, esq);
    hipLaunchKernelGGL(zsq_pw, dim3(NTOT / 256), dim3(256), 0, stream, z, zsq);
    hipLaunchKernelGGL(split_e, dim3((Kc * Cc + 255) / 256), dim3(256), 0, stream, key, ef16);
    hipLaunchKernelGGL(split_z, dim3(NTOT / 64), dim3(256), 0, stream, z, zf16);
    hipLaunchKernelGGL(screen, dim3(SBLK), dim3(256), 0, stream,
                       zf16, ef16, esq, zsq, cand, cnt);
    hipLaunchKernelGGL(finalize, dim3(EBLKS), dim3(256), 0, stream,
                       z, key, val, esq, zsq, cand, cnt, out, partial);
    hipLaunchKernelGGL(fin_kernel, dim3(1), dim3(256), 0, stream, partial, out + ZQV + NTOT);
}

// Round 10
// 837.994 us; speedup vs baseline: 1.1976x; 1.0400x over previous
//
#include <hip/hip_runtime.h>
#include <stdint.h>

constexpr int Cc   = 256;
constexpr int Kc   = 1024;
constexpr int NLOC = 16 * 56 * 56;      // 50176
constexpr int NB   = 2;
constexpr int NTOT = NB * NLOC;         // 100352
constexpr long long ZQV = (long long)NB * Cc * NLOC;  // 25690112

// screen tiling: one block = 128 rows x 128 codes, K=256 in 4 chunks of 64
constexpr int SR   = 128;
constexpr int SC   = 128;
constexpr int BK   = 64;
constexpr int NCH  = Cc / BK;           // 4
constexpr int NRT  = NTOT / SR;         // 784
constexpr int NSL  = Kc / SC;           // 8
constexpr int SBLK = NRT * NSL;         // 6272

constexpr int   SLOTS = 16;
constexpr float WIN   = 3e-4f;          // >> f16-screen error bound (~6e-5)
constexpr float NEG2S = -0.001953125f;  // -2/1024 (exact descale)

constexpr int EB = 64, EBLKS = NTOT / EB;  // 1568

using f16x8 = __attribute__((ext_vector_type(8))) _Float16;
using f32x4 = __attribute__((ext_vector_type(4))) float;
typedef unsigned long long u64;
typedef unsigned int       u32;
typedef unsigned short     u16;

// ---------------------------------------------------------------------------
// numpy-exact helpers (validated, unchanged)
// ---------------------------------------------------------------------------
__device__ __forceinline__ float sqf(float x) {
    float s = x * x;
    asm("" : "+v"(s));
    return s;
}

template <typename Loader>
__device__ __forceinline__ float pw256_sq(Loader ld)
{
    float half[2];
    #pragma unroll
    for (int h = 0; h < 2; ++h) {
        float r[8];
        #pragma unroll
        for (int j = 0; j < 8; ++j) r[j] = sqf(ld(h * 128 + j));
        #pragma unroll
        for (int i = 8; i < 128; i += 8)
            #pragma unroll
            for (int j = 0; j < 8; ++j) r[j] += sqf(ld(h * 128 + i + j));
        half[h] = ((r[0] + r[1]) + (r[2] + r[3])) + ((r[4] + r[5]) + (r[6] + r[7]));
    }
    return half[0] + half[1];
}

__global__ void esq_pw(const float* __restrict__ key, float* __restrict__ esq)
{
    int k = blockIdx.x * 256 + threadIdx.x;
    if (k < Kc) {
        const float* a = key + (size_t)k * Cc;
        esq[k] = pw256_sq([&](int c) { return a[c]; });
    }
}

__global__ void zsq_pw(const float* __restrict__ z, float* __restrict__ zsq)
{
    int p = blockIdx.x * 256 + threadIdx.x;
    int b = p / NLOC, loc = p - b * NLOC;
    const float* a = z + (size_t)b * Cc * NLOC + loc;
    zsq[p] = pw256_sq([&](int c) { return a[(size_t)c * NLOC]; });
}

__device__ __forceinline__ u16 f16b(float x)
{
    _Float16 h = (_Float16)x;   // v_cvt_f16_f32, RNE
    u16 r;
    __builtin_memcpy(&r, &h, 2);
    return r;
}

// split_e: ef16[k][c] = f16(key[k][c] * 1024)  (exact pow-2 scale)
__global__ void split_e(const float* __restrict__ key, u16* __restrict__ ef16)
{
    int i = blockIdx.x * 256 + threadIdx.x;
    if (i < Kc * Cc) ef16[i] = f16b(key[i] * 1024.0f);
}

// split_z: z [B][C][NLOC] f32 -> zf16 [NTOT][C] f16 (transposed rows)
__global__ __launch_bounds__(256, 2)
void split_z(const float* __restrict__ z, u16* __restrict__ zf16)
{
    __shared__ float t[64][260];
    const int tid = threadIdx.x;
    const int n0  = blockIdx.x * 64;
    const int b   = (n0 >= NLOC) ? 1 : 0;
    const int loc0 = n0 - b * NLOC;
    const float* zb = z + (size_t)b * Cc * NLOC;

    {
        const int n4 = tid & 15;
        #pragma unroll
        for (int it = 0; it < 4; ++it) {
            int c4 = (tid >> 4) + it * 16;
            float4 g0 = *reinterpret_cast<const float4*>(zb + (size_t)(c4 * 4 + 0) * NLOC + loc0 + n4 * 4);
            float4 g1 = *reinterpret_cast<const float4*>(zb + (size_t)(c4 * 4 + 1) * NLOC + loc0 + n4 * 4);
            float4 g2 = *reinterpret_cast<const float4*>(zb + (size_t)(c4 * 4 + 2) * NLOC + loc0 + n4 * 4);
            float4 g3 = *reinterpret_cast<const float4*>(zb + (size_t)(c4 * 4 + 3) * NLOC + loc0 + n4 * 4);
            *reinterpret_cast<float4*>(&t[n4 * 4 + 0][c4 * 4]) = make_float4(g0.x, g1.x, g2.x, g3.x);
            *reinterpret_cast<float4*>(&t[n4 * 4 + 1][c4 * 4]) = make_float4(g0.y, g1.y, g2.y, g3.y);
            *reinterpret_cast<float4*>(&t[n4 * 4 + 2][c4 * 4]) = make_float4(g0.z, g1.z, g2.z, g3.z);
            *reinterpret_cast<float4*>(&t[n4 * 4 + 3][c4 * 4]) = make_float4(g0.w, g1.w, g2.w, g3.w);
        }
    }
    __syncthreads();
    {
        const int row2 = tid >> 5;
        const int ch   = tid & 31;
        #pragma unroll
        for (int rg = 0; rg < 8; ++rg) {
            int row = rg * 8 + row2;
            float4 f0 = *reinterpret_cast<const float4*>(&t[row][ch * 8]);
            float4 f1 = *reinterpret_cast<const float4*>(&t[row][ch * 8 + 4]);
            float xs[8] = {f0.x, f0.y, f0.z, f0.w, f1.x, f1.y, f1.z, f1.w};
            u32 hp[4];
            #pragma unroll
            for (int j = 0; j < 4; ++j)
                hp[j] = (u32)f16b(xs[2 * j]) | ((u32)f16b(xs[2 * j + 1]) << 16);
            *reinterpret_cast<uint4*>(zf16 + ((size_t)(n0 + row)) * Cc + ch * 8) =
                make_uint4(hp[0], hp[1], hp[2], hp[3]);
        }
    }
}

// global -> LDS direct, 16B/lane (dest = uniform base + lane*16)
__device__ __forceinline__ void gload16(const u16* g, u16* lds)
{
    __builtin_amdgcn_global_load_lds(
        (const __attribute__((address_space(1))) u32*)g,
        (__attribute__((address_space(3))) u32*)lds, 16, 0, 0);
}

// ---------------------------------------------------------------------------
// screen: f16 MFMA GEMM, m97-style 128x128 tile, BK=64, single-buffered LDS,
// 3-4 blocks/CU co-resident. Per block: slice-min per row over its 128 codes
// + window emission of candidates.
// ---------------------------------------------------------------------------
__global__ __launch_bounds__(256, 3)
void screen(const u16* __restrict__ zf16, const u16* __restrict__ ef16,
            const float* __restrict__ esq, const float* __restrict__ zsq,
            u64* __restrict__ cand, int* __restrict__ cnt)
{
    __shared__ u16  A_lds[SR * BK];    // 16 KB, [row][8 granules of 8 f16], XOR-swz
    __shared__ u16  B_lds[SC * BK];    // 16 KB
    __shared__ u64  gm[2][SR];         // 2 KB
    __shared__ float esq_s[SC];
    __shared__ float zsq_s[SR];

    const int tid = threadIdx.x;
    const int bid = blockIdx.x;
    const int r0  = (bid >> 3) * SR;       // row tile
    const int k0  = (bid & 7) * SC;        // code slice
    const int wid = tid >> 6, l = tid & 63;
    const int wr  = wid >> 1, wc = wid & 1;

    for (int i = tid; i < SC; i += 256) esq_s[i] = esq[k0 + i];
    for (int i = tid; i < SR; i += 256) zsq_s[i] = zsq[r0 + i];

    f32x4 acc[4][4];
    #pragma unroll
    for (int i = 0; i < 4; ++i)
        #pragma unroll
        for (int j = 0; j < 4; ++j)
            acc[i][j] = f32x4{0.f, 0.f, 0.f, 0.f};

    for (int ch = 0; ch < NCH; ++ch) {
        __syncthreads();   // previous chunk fully consumed (covers esq_s on ch=0)
        // stage A chunk: 4 gload16/wave; lane l -> row rowb+(l>>3), dest granule l&7.
        // source supplies logical granule (l&7)^(row&7)  (inverse swizzle).
        {
            const int lr = l >> 3;
            #pragma unroll
            for (int t = 0; t < 4; ++t) {
                int rowb = wid * 32 + t * 8;
                int row  = rowb + lr;
                int g    = (l & 7) ^ (row & 7);
                gload16(zf16 + (size_t)(r0 + row) * Cc + ch * BK + g * 8,
                        A_lds + rowb * BK);
                gload16(ef16 + (size_t)(k0 + row) * Cc + ch * BK + g * 8,
                        B_lds + rowb * BK);
            }
        }
        __syncthreads();   // vmcnt drained

        #pragma unroll
        for (int kk = 0; kk < 2; ++kk) {
            f16x8 af[4], bf[4];
            const int G = kk * 4 + (l >> 4);
            #pragma unroll
            for (int i = 0; i < 4; ++i) {
                int row = wr * 64 + i * 16 + (l & 15);
                int pg  = G ^ (row & 7);
                af[i] = *reinterpret_cast<const f16x8*>(&A_lds[row * BK + pg * 8]);
            }
            #pragma unroll
            for (int j = 0; j < 4; ++j) {
                int col = wc * 64 + j * 16 + (l & 15);
                int pg  = G ^ (col & 7);
                bf[j] = *reinterpret_cast<const f16x8*>(&B_lds[col * BK + pg * 8]);
            }
            #pragma unroll
            for (int i = 0; i < 4; ++i)
                #pragma unroll
                for (int j = 0; j < 4; ++j)
                    acc[i][j] = __builtin_amdgcn_mfma_f32_16x16x32_f16(
                        af[i], bf[j], acc[i][j], 0, 0, 0);
        }
    }

    // ---- epilogue: slice-min per row, then window emission ----
    #pragma unroll
    for (int i = 0; i < 4; ++i) {
        #pragma unroll
        for (int r = 0; r < 4; ++r) {
            int rloc = wr * 64 + i * 16 + ((l >> 4) << 2) + r;
            float zq = zsq_s[rloc];
            u64 mn = 0xFFFFFFFFFFFFFFFFull;
            #pragma unroll
            for (int j = 0; j < 4; ++j) {
                int cl = wc * 64 + j * 16 + (l & 15);
                float t = zq + esq_s[cl];
                float d = fmaf(NEG2S, acc[i][j][r], t);
                u64 pk = ((u64)__float_as_uint(d) << 32) | (u32)(k0 + cl);
                mn = pk < mn ? pk : mn;
            }
            #pragma unroll
            for (int m = 1; m < 16; m <<= 1) {   // reduce over the 16 col-lanes
                u64 o = __shfl_xor(mn, m, 64);
                mn = o < mn ? o : mn;
            }
            if ((l & 15) == 0) gm[wc][rloc] = mn;
        }
    }
    __syncthreads();

    #pragma unroll
    for (int i = 0; i < 4; ++i) {
        #pragma unroll
        for (int r = 0; r < 4; ++r) {
            int rloc = wr * 64 + i * 16 + ((l >> 4) << 2) + r;
            u64 m0 = gm[0][rloc], m1 = gm[1][rloc];
            u64 sm = m0 < m1 ? m0 : m1;
            float thr = __uint_as_float((u32)(sm >> 32)) + WIN;
            float zq = zsq_s[rloc];
            int rg = r0 + rloc;
            #pragma unroll
            for (int j = 0; j < 4; ++j) {
                int cl = wc * 64 + j * 16 + (l & 15);
                float t = zq + esq_s[cl];
                float d = fmaf(NEG2S, acc[i][j][r], t);
                if (d <= thr) {
                    int slot = atomicAdd(&cnt[rg], 1);
                    if (slot < SLOTS)
                        cand[(size_t)rg * SLOTS + slot] =
                            ((u64)__float_as_uint(d) << 32) | (u32)(k0 + cl);
                }
            }
        }
    }
}

// ---------------------------------------------------------------------------
// finalize: np-exact argmin from candidates (rescore ambiguous rows), then
// LDS-staged coalesced gather of val/key rows; f64 loss partials.
// ---------------------------------------------------------------------------
__global__ __launch_bounds__(256, 2)
void finalize(const float* __restrict__ z, const float* __restrict__ key,
              const float* __restrict__ val,
              const float* __restrict__ esq, const float* __restrict__ zsq,
              const u64* __restrict__ cand, const int* __restrict__ cnt,
              float* __restrict__ out, double* __restrict__ partial)
{
    __shared__ float rowbuf[EB][261];   // 66.8 KB; 261 -> stride 5 banks (2-way reads)
    __shared__ int idx_sh[EB];
    __shared__ double wred[4];
    const int tid = threadIdx.x, blk = blockIdx.x;
    const int wid = tid >> 6, l = tid & 63;
    const int p0  = blk * EB;
    const int b   = (p0 >= NLOC) ? 1 : 0;
    const int loc0 = p0 - b * NLOC;
    const float* zb = z + (size_t)b * Cc * NLOC;

    // phase 1: per-row candidate resolution (np-exact semantics, unchanged)
    if (tid < EB) {
        const int p = p0 + tid;
        const int c = cnt[p];
        const int n = (c < SLOTS) ? c : SLOTS;
        u64 best = 0xFFFFFFFFFFFFFFFFull;
        for (int s = 0; s < n; ++s) {
            u64 v = cand[(size_t)p * SLOTS + s];
            if (v < best) best = v;
        }
        int kbest = (int)(u32)best;
        const float db = __uint_as_float((u32)(best >> 32));

        if (c > SLOTS) {
            // overflow backstop: full np-exact scan
            u64 bb = 0xFFFFFFFFFFFFFFFFull;
            for (int k = 0; k < Kc; ++k) {
                const float* kr = key + (size_t)k * Cc;
                float m = 0.f;
                for (int cc = 0; cc < Cc; ++cc)
                    m = fmaf(zb[(size_t)cc * NLOC + loc0 + tid], kr[cc], m);
                float t = zsq[p] + esq[k];
                float d = fmaf(-2.0f, m, t);
                u64 pk = ((u64)__float_as_uint(d) << 32) | (u32)k;
                if (pk < bb) bb = pk;
            }
            kbest = (int)(u32)bb;
        } else {
            int namb = 0;
            for (int s = 0; s < n; ++s) {
                float dv = __uint_as_float((u32)(cand[(size_t)p * SLOTS + s] >> 32));
                namb += (dv <= db + WIN) ? 1 : 0;
            }
            if (namb > 1) {
                u64 bb = 0xFFFFFFFFFFFFFFFFull;
                for (int s = 0; s < n; ++s) {
                    u64 v = cand[(size_t)p * SLOTS + s];
                    float dv = __uint_as_float((u32)(v >> 32));
                    if (dv <= db + WIN) {
                        int k = (int)(u32)v;
                        const float* kr = key + (size_t)k * Cc;
                        float m = 0.f;
                        for (int cc = 0; cc < Cc; ++cc)
                            m = fmaf(zb[(size_t)cc * NLOC + loc0 + tid], kr[cc], m);
                        float t = zsq[p] + esq[k];
                        float d = fmaf(-2.0f, m, t);
                        u64 pk = ((u64)__float_as_uint(d) << 32) | (u32)k;
                        if (pk < bb) bb = pk;
                    }
                }
                kbest = (int)(u32)bb;
            }
        }
        idx_sh[tid] = kbest;
        out[ZQV + p] = (float)kbest;
    }
    __syncthreads();

    // phase 2: stage val rows coalesced (wave per row)
    for (int r = wid; r < EB; r += 4) {
        float4 v = *reinterpret_cast<const float4*>(val + (size_t)idx_sh[r] * Cc + l * 4);
        *reinterpret_cast<float4*>(&rowbuf[r][l * 4]) = v;
    }
    __syncthreads();

    // phase 3: write z_q_value coalesced (lane = n, c wave-uniform)
    #pragma unroll 4
    for (int it = 0; it < 64; ++it) {
        int c = wid + it * 4;
        out[((size_t)b * Cc + c) * NLOC + loc0 + l] = rowbuf[l][c];
    }
    __syncthreads();

    // phase 4: stage key rows coalesced
    for (int r = wid; r < EB; r += 4) {
        float4 v = *reinterpret_cast<const float4*>(key + (size_t)idx_sh[r] * Cc + l * 4);
        *reinterpret_cast<float4*>(&rowbuf[r][l * 4]) = v;
    }
    __syncthreads();

    // phase 5: f64 loss (z read coalesced, key from LDS)
    double lacc = 0.0;
    #pragma unroll 4
    for (int it = 0; it < 64; ++it) {
        int c = wid + it * 4;
        double diff = (double)rowbuf[l][c]
                    - (double)zb[(size_t)c * NLOC + loc0 + l];
        lacc = fma(diff, diff, lacc);
    }
    for (int off = 32; off > 0; off >>= 1) lacc += __shfl_down(lacc, off);
    if (l == 0) wred[wid] = lacc;
    __syncthreads();
    if (tid == 0) partial[blk] = wred[0] + wred[1] + wred[2] + wred[3];
}

__global__ void fin_kernel(const double* __restrict__ partial, float* __restrict__ out_loss)
{
    __shared__ double sh[256];
    double s = 0.0;
    for (int i = threadIdx.x; i < EBLKS; i += 256) s += partial[i];
    sh[threadIdx.x] = s;
    __syncthreads();
    for (int st = 128; st > 0; st >>= 1) {
        if (threadIdx.x < st) sh[threadIdx.x] += sh[threadIdx.x + st];
        __syncthreads();
    }
    if (threadIdx.x == 0)
        out_loss[0] = (float)(1.25 * sh[0] / (double)((long long)NTOT * Cc));
}

// ---------------------------------------------------------------------------
extern "C" void kernel_launch(void* const* d_in, const int* in_sizes, int n_in,
                              void* d_out, int out_size, void* d_ws, size_t ws_size,
                              hipStream_t stream)
{
    const float* z   = (const float*)d_in[0];
    const float* key = (const float*)d_in[1];
    const float* val = (const float*)d_in[2];
    float* out = (float*)d_out;

    // zf16 scratch lives in the z_q_value output region (dead before finalize)
    u16* zf16 = (u16*)d_out;

    u16*    ef16    = (u16*)d_ws;                              // 512 KB
    u64*    cand    = (u64*)(ef16 + (size_t)Kc * Cc);          // 12.85 MB
    int*    cnt     = (int*)(cand + (size_t)NTOT * SLOTS);     // 401 KB
    double* partial = (double*)(cnt + NTOT);                   // 12.5 KB
    float*  esq     = (float*)(partial + EBLKS);               // 4 KB
    float*  zsq     = esq + Kc;                                // 401 KB

    hipMemsetAsync(cnt, 0, NTOT * sizeof(int), stream);
    hipLaunchKernelGGL(esq_pw, dim3((Kc + 255) / 256), dim3(256), 0, stream, key, esq);
    hipLaunchKernelGGL(zsq_pw, dim3(NTOT / 256), dim3(256), 0, stream, z, zsq);
    hipLaunchKernelGGL(split_e, dim3((Kc * Cc + 255) / 256), dim3(256), 0, stream, key, ef16);
    hipLaunchKernelGGL(split_z, dim3(NTOT / 64), dim3(256), 0, stream, z, zf16);
    hipLaunchKernelGGL(screen, dim3(SBLK), dim3(256), 0, stream,
                       zf16, ef16, esq, zsq, cand, cnt);
    hipLaunchKernelGGL(finalize, dim3(EBLKS), dim3(256), 0, stream,
                       z, key, val, esq, zsq, cand, cnt, out, partial);
    hipLaunchKernelGGL(fin_kernel, dim3(1), dim3(256), 0, stream, partial, out + ZQV + NTOT);
}

// Round 11
// 688.324 us; speedup vs baseline: 1.4580x; 1.2174x over previous
//
#include <hip/hip_runtime.h>
#include <stdint.h>

constexpr int Cc   = 256;
constexpr int Kc   = 1024;
constexpr int NLOC = 16 * 56 * 56;      // 50176
constexpr int NB   = 2;
constexpr int NTOT = NB * NLOC;         // 100352
constexpr long long ZQV = (long long)NB * Cc * NLOC;  // 25690112

// screen tiling: one block = 128 rows x 128 codes, K=256 in 4 chunks of 64
constexpr int SR   = 128;
constexpr int SC   = 128;
constexpr int BK   = 64;
constexpr int NCH  = Cc / BK;           // 4
constexpr int NRT  = NTOT / SR;         // 784
constexpr int NSL  = Kc / SC;           // 8
constexpr int SBLK = NRT * NSL;         // 6272

constexpr int   SLOTS = 16;
constexpr float WIN   = 3e-4f;          // validated (absmax 0 twice at 3e-4)
constexpr float NEG2S = -0.001953125f;  // -2/1024 (exact descale)

constexpr int F1B = NTOT / 256;         // 392 resolve blocks
constexpr int RB  = 32;                 // rows per gather block
constexpr int F2B = NTOT / RB;          // 3136 gather blocks

using f16x8 = __attribute__((ext_vector_type(8))) _Float16;
using f32x4 = __attribute__((ext_vector_type(4))) float;
typedef unsigned long long u64;
typedef unsigned int       u32;
typedef unsigned short     u16;

// ---------------------------------------------------------------------------
// numpy-exact helpers (validated, unchanged)
// ---------------------------------------------------------------------------
__device__ __forceinline__ float sqf(float x) {
    float s = x * x;
    asm("" : "+v"(s));
    return s;
}

template <typename Loader>
__device__ __forceinline__ float pw256_sq(Loader ld)
{
    float half[2];
    #pragma unroll
    for (int h = 0; h < 2; ++h) {
        float r[8];
        #pragma unroll
        for (int j = 0; j < 8; ++j) r[j] = sqf(ld(h * 128 + j));
        #pragma unroll
        for (int i = 8; i < 128; i += 8)
            #pragma unroll
            for (int j = 0; j < 8; ++j) r[j] += sqf(ld(h * 128 + i + j));
        half[h] = ((r[0] + r[1]) + (r[2] + r[3])) + ((r[4] + r[5]) + (r[6] + r[7]));
    }
    return half[0] + half[1];
}

__global__ void esq_pw(const float* __restrict__ key, float* __restrict__ esq)
{
    int k = blockIdx.x * 256 + threadIdx.x;
    if (k < Kc) {
        const float* a = key + (size_t)k * Cc;
        esq[k] = pw256_sq([&](int c) { return a[c]; });
    }
}

__global__ void zsq_pw(const float* __restrict__ z, float* __restrict__ zsq)
{
    int p = blockIdx.x * 256 + threadIdx.x;
    int b = p / NLOC, loc = p - b * NLOC;
    const float* a = z + (size_t)b * Cc * NLOC + loc;
    zsq[p] = pw256_sq([&](int c) { return a[(size_t)c * NLOC]; });
}

__device__ __forceinline__ u16 f16b(float x)
{
    _Float16 h = (_Float16)x;   // v_cvt_f16_f32, RNE
    u16 r;
    __builtin_memcpy(&r, &h, 2);
    return r;
}

// split_e: ef16[k][c] = f16(key[k][c] * 1024)  (exact pow-2 scale)
__global__ void split_e(const float* __restrict__ key, u16* __restrict__ ef16)
{
    int i = blockIdx.x * 256 + threadIdx.x;
    if (i < Kc * Cc) ef16[i] = f16b(key[i] * 1024.0f);
}

// split_z: z [B][C][NLOC] f32 -> zf16 [NTOT][C] f16 (transposed rows)
__global__ __launch_bounds__(256, 2)
void split_z(const float* __restrict__ z, u16* __restrict__ zf16)
{
    __shared__ float t[64][260];
    const int tid = threadIdx.x;
    const int n0  = blockIdx.x * 64;
    const int b   = (n0 >= NLOC) ? 1 : 0;
    const int loc0 = n0 - b * NLOC;
    const float* zb = z + (size_t)b * Cc * NLOC;

    {
        const int n4 = tid & 15;
        #pragma unroll
        for (int it = 0; it < 4; ++it) {
            int c4 = (tid >> 4) + it * 16;
            float4 g0 = *reinterpret_cast<const float4*>(zb + (size_t)(c4 * 4 + 0) * NLOC + loc0 + n4 * 4);
            float4 g1 = *reinterpret_cast<const float4*>(zb + (size_t)(c4 * 4 + 1) * NLOC + loc0 + n4 * 4);
            float4 g2 = *reinterpret_cast<const float4*>(zb + (size_t)(c4 * 4 + 2) * NLOC + loc0 + n4 * 4);
            float4 g3 = *reinterpret_cast<const float4*>(zb + (size_t)(c4 * 4 + 3) * NLOC + loc0 + n4 * 4);
            *reinterpret_cast<float4*>(&t[n4 * 4 + 0][c4 * 4]) = make_float4(g0.x, g1.x, g2.x, g3.x);
            *reinterpret_cast<float4*>(&t[n4 * 4 + 1][c4 * 4]) = make_float4(g0.y, g1.y, g2.y, g3.y);
            *reinterpret_cast<float4*>(&t[n4 * 4 + 2][c4 * 4]) = make_float4(g0.z, g1.z, g2.z, g3.z);
            *reinterpret_cast<float4*>(&t[n4 * 4 + 3][c4 * 4]) = make_float4(g0.w, g1.w, g2.w, g3.w);
        }
    }
    __syncthreads();
    {
        const int row2 = tid >> 5;
        const int ch   = tid & 31;
        #pragma unroll
        for (int rg = 0; rg < 8; ++rg) {
            int row = rg * 8 + row2;
            float4 f0 = *reinterpret_cast<const float4*>(&t[row][ch * 8]);
            float4 f1 = *reinterpret_cast<const float4*>(&t[row][ch * 8 + 4]);
            float xs[8] = {f0.x, f0.y, f0.z, f0.w, f1.x, f1.y, f1.z, f1.w};
            u32 hp[4];
            #pragma unroll
            for (int j = 0; j < 4; ++j)
                hp[j] = (u32)f16b(xs[2 * j]) | ((u32)f16b(xs[2 * j + 1]) << 16);
            *reinterpret_cast<uint4*>(zf16 + ((size_t)(n0 + row)) * Cc + ch * 8) =
                make_uint4(hp[0], hp[1], hp[2], hp[3]);
        }
    }
}

// global -> LDS direct, 16B/lane (dest = uniform base + lane*16)
__device__ __forceinline__ void gload16(const u16* g, u16* lds)
{
    __builtin_amdgcn_global_load_lds(
        (const __attribute__((address_space(1))) u32*)g,
        (__attribute__((address_space(3))) u32*)lds, 16, 0, 0);
}

// ---------------------------------------------------------------------------
// screen: f16 MFMA GEMM, m97-style 128x128 tile, BK=64 — UNCHANGED from R10
// ---------------------------------------------------------------------------
__global__ __launch_bounds__(256, 3)
void screen(const u16* __restrict__ zf16, const u16* __restrict__ ef16,
            const float* __restrict__ esq, const float* __restrict__ zsq,
            u64* __restrict__ cand, int* __restrict__ cnt)
{
    __shared__ u16  A_lds[SR * BK];    // 16 KB
    __shared__ u16  B_lds[SC * BK];    // 16 KB
    __shared__ u64  gm[2][SR];         // 2 KB
    __shared__ float esq_s[SC];
    __shared__ float zsq_s[SR];

    const int tid = threadIdx.x;
    const int bid = blockIdx.x;
    const int r0  = (bid >> 3) * SR;
    const int k0  = (bid & 7) * SC;
    const int wid = tid >> 6, l = tid & 63;
    const int wr  = wid >> 1, wc = wid & 1;

    for (int i = tid; i < SC; i += 256) esq_s[i] = esq[k0 + i];
    for (int i = tid; i < SR; i += 256) zsq_s[i] = zsq[r0 + i];

    f32x4 acc[4][4];
    #pragma unroll
    for (int i = 0; i < 4; ++i)
        #pragma unroll
        for (int j = 0; j < 4; ++j)
            acc[i][j] = f32x4{0.f, 0.f, 0.f, 0.f};

    for (int ch = 0; ch < NCH; ++ch) {
        __syncthreads();
        {
            const int lr = l >> 3;
            #pragma unroll
            for (int t = 0; t < 4; ++t) {
                int rowb = wid * 32 + t * 8;
                int row  = rowb + lr;
                int g    = (l & 7) ^ (row & 7);
                gload16(zf16 + (size_t)(r0 + row) * Cc + ch * BK + g * 8,
                        A_lds + rowb * BK);
                gload16(ef16 + (size_t)(k0 + row) * Cc + ch * BK + g * 8,
                        B_lds + rowb * BK);
            }
        }
        __syncthreads();

        #pragma unroll
        for (int kk = 0; kk < 2; ++kk) {
            f16x8 af[4], bf[4];
            const int G = kk * 4 + (l >> 4);
            #pragma unroll
            for (int i = 0; i < 4; ++i) {
                int row = wr * 64 + i * 16 + (l & 15);
                int pg  = G ^ (row & 7);
                af[i] = *reinterpret_cast<const f16x8*>(&A_lds[row * BK + pg * 8]);
            }
            #pragma unroll
            for (int j = 0; j < 4; ++j) {
                int col = wc * 64 + j * 16 + (l & 15);
                int pg  = G ^ (col & 7);
                bf[j] = *reinterpret_cast<const f16x8*>(&B_lds[col * BK + pg * 8]);
            }
            #pragma unroll
            for (int i = 0; i < 4; ++i)
                #pragma unroll
                for (int j = 0; j < 4; ++j)
                    acc[i][j] = __builtin_amdgcn_mfma_f32_16x16x32_f16(
                        af[i], bf[j], acc[i][j], 0, 0, 0);
        }
    }

    #pragma unroll
    for (int i = 0; i < 4; ++i) {
        #pragma unroll
        for (int r = 0; r < 4; ++r) {
            int rloc = wr * 64 + i * 16 + ((l >> 4) << 2) + r;
            float zq = zsq_s[rloc];
            u64 mn = 0xFFFFFFFFFFFFFFFFull;
            #pragma unroll
            for (int j = 0; j < 4; ++j) {
                int cl = wc * 64 + j * 16 + (l & 15);
                float t = zq + esq_s[cl];
                float d = fmaf(NEG2S, acc[i][j][r], t);
                u64 pk = ((u64)__float_as_uint(d) << 32) | (u32)(k0 + cl);
                mn = pk < mn ? pk : mn;
            }
            #pragma unroll
            for (int m = 1; m < 16; m <<= 1) {
                u64 o = __shfl_xor(mn, m, 64);
                mn = o < mn ? o : mn;
            }
            if ((l & 15) == 0) gm[wc][rloc] = mn;
        }
    }
    __syncthreads();

    #pragma unroll
    for (int i = 0; i < 4; ++i) {
        #pragma unroll
        for (int r = 0; r < 4; ++r) {
            int rloc = wr * 64 + i * 16 + ((l >> 4) << 2) + r;
            u64 m0 = gm[0][rloc], m1 = gm[1][rloc];
            u64 sm = m0 < m1 ? m0 : m1;
            float thr = __uint_as_float((u32)(sm >> 32)) + WIN;
            float zq = zsq_s[rloc];
            int rg = r0 + rloc;
            #pragma unroll
            for (int j = 0; j < 4; ++j) {
                int cl = wc * 64 + j * 16 + (l & 15);
                float t = zq + esq_s[cl];
                float d = fmaf(NEG2S, acc[i][j][r], t);
                if (d <= thr) {
                    int slot = atomicAdd(&cnt[rg], 1);
                    if (slot < SLOTS)
                        cand[(size_t)rg * SLOTS + slot] =
                            ((u64)__float_as_uint(d) << 32) | (u32)(k0 + cl);
                }
            }
        }
    }
}

// ---------------------------------------------------------------------------
// F1 resolve: one thread per row; np-exact candidate resolution.
// All 256 threads active; no big LDS -> high occupancy.
// ---------------------------------------------------------------------------
__global__ __launch_bounds__(256)
void resolve(const float* __restrict__ z, const float* __restrict__ key,
             const float* __restrict__ esq, const float* __restrict__ zsq,
             const u64* __restrict__ cand, const int* __restrict__ cnt,
             float* __restrict__ out, int* __restrict__ idxw)
{
    const int p   = blockIdx.x * 256 + threadIdx.x;   // global row
    const int b   = (p >= NLOC) ? 1 : 0;              // uniform per block (NLOC%256==0)
    const int loc = p - b * NLOC;
    const float* zb = z + (size_t)b * Cc * NLOC;

    const int c = cnt[p];
    const int n = (c < SLOTS) ? c : SLOTS;
    u64 best = 0xFFFFFFFFFFFFFFFFull;
    for (int s = 0; s < n; ++s) {
        u64 v = cand[(size_t)p * SLOTS + s];
        if (v < best) best = v;
    }
    int kbest = (int)(u32)best;
    const float db = __uint_as_float((u32)(best >> 32));

    if (c > SLOTS) {
        // overflow backstop: full np-exact scan (z reads coalesced across threads)
        u64 bb = 0xFFFFFFFFFFFFFFFFull;
        for (int k = 0; k < Kc; ++k) {
            const float* kr = key + (size_t)k * Cc;
            float m = 0.f;
            for (int cc = 0; cc < Cc; ++cc)
                m = fmaf(zb[(size_t)cc * NLOC + loc], kr[cc], m);
            float t = zsq[p] + esq[k];
            float d = fmaf(-2.0f, m, t);
            u64 pk = ((u64)__float_as_uint(d) << 32) | (u32)k;
            if (pk < bb) bb = pk;
        }
        kbest = (int)(u32)bb;
    } else {
        int namb = 0;
        for (int s = 0; s < n; ++s) {
            float dv = __uint_as_float((u32)(cand[(size_t)p * SLOTS + s] >> 32));
            namb += (dv <= db + WIN) ? 1 : 0;
        }
        if (namb > 1) {
            u64 bb = 0xFFFFFFFFFFFFFFFFull;
            for (int s = 0; s < n; ++s) {
                u64 v = cand[(size_t)p * SLOTS + s];
                float dv = __uint_as_float((u32)(v >> 32));
                if (dv <= db + WIN) {
                    int k = (int)(u32)v;
                    const float* kr = key + (size_t)k * Cc;
                    float m = 0.f;
                    for (int cc = 0; cc < Cc; ++cc)
                        m = fmaf(zb[(size_t)cc * NLOC + loc], kr[cc], m);
                    float t = zsq[p] + esq[k];
                    float d = fmaf(-2.0f, m, t);
                    u64 pk = ((u64)__float_as_uint(d) << 32) | (u32)k;
                    if (pk < bb) bb = pk;
                }
            }
            kbest = (int)(u32)bb;
        }
    }
    idxw[p] = kbest;
    out[ZQV + p] = (float)kbest;
}

// ---------------------------------------------------------------------------
// F2 gather: 32 rows/block; LDS row staging (33 KB -> ~4 blocks/CU);
// float4 out-writes and z reads; f64 loss partials.
// ---------------------------------------------------------------------------
__global__ __launch_bounds__(256)
void gather(const float* __restrict__ z, const float* __restrict__ key,
            const float* __restrict__ val, const int* __restrict__ idxw,
            float* __restrict__ out, double* __restrict__ partial)
{
    __shared__ float rowbuf[RB][261];   // 33.4 KB; 261 -> n-quad reads hit 8 banks
    __shared__ int   idx_sh[RB];
    __shared__ double wred[4];
    const int tid = threadIdx.x, blk = blockIdx.x;
    const int wid = tid >> 6, l = tid & 63;
    const int p0  = blk * RB;
    const int b   = (p0 >= NLOC) ? 1 : 0;
    const int loc0 = p0 - b * NLOC;
    const float* zb = z + (size_t)b * Cc * NLOC;

    if (tid < RB) idx_sh[tid] = idxw[p0 + tid];
    __syncthreads();

    // stage val rows coalesced: one full row (1 KB) per wave-instr
    #pragma unroll
    for (int i = 0; i < RB / 4; ++i) {
        int row = wid * (RB / 4) + i;
        float4 v = *reinterpret_cast<const float4*>(val + (size_t)idx_sh[row] * Cc + l * 4);
        *reinterpret_cast<float4*>(&rowbuf[row][l * 4]) = v;
    }
    __syncthreads();

    // write z_q_value: lane covers n-quad (4 n), 8 c's per instr, float4 stores
    const int nq = l & 7;
    #pragma unroll 4
    for (int it = 0; it < 32; ++it) {
        int cc = (l >> 3) + 8 * it;
        float4 v = make_float4(rowbuf[nq * 4 + 0][cc], rowbuf[nq * 4 + 1][cc],
                               rowbuf[nq * 4 + 2][cc], rowbuf[nq * 4 + 3][cc]);
        *reinterpret_cast<float4*>(
            out + ((size_t)b * Cc + cc) * NLOC + loc0 + nq * 4) = v;
    }
    __syncthreads();

    // stage key rows coalesced
    #pragma unroll
    for (int i = 0; i < RB / 4; ++i) {
        int row = wid * (RB / 4) + i;
        float4 v = *reinterpret_cast<const float4*>(key + (size_t)idx_sh[row] * Cc + l * 4);
        *reinterpret_cast<float4*>(&rowbuf[row][l * 4]) = v;
    }
    __syncthreads();

    // f64 loss: float4 z reads, key from LDS
    double lacc = 0.0;
    #pragma unroll 4
    for (int it = 0; it < 32; ++it) {
        int cc = (l >> 3) + 8 * it;
        float4 zv = *reinterpret_cast<const float4*>(
            zb + (size_t)cc * NLOC + loc0 + nq * 4);
        double d0 = (double)rowbuf[nq * 4 + 0][cc] - (double)zv.x;
        double d1 = (double)rowbuf[nq * 4 + 1][cc] - (double)zv.y;
        double d2 = (double)rowbuf[nq * 4 + 2][cc] - (double)zv.z;
        double d3 = (double)rowbuf[nq * 4 + 3][cc] - (double)zv.w;
        lacc = fma(d0, d0, lacc); lacc = fma(d1, d1, lacc);
        lacc = fma(d2, d2, lacc); lacc = fma(d3, d3, lacc);
    }
    for (int off = 32; off > 0; off >>= 1) lacc += __shfl_down(lacc, off);
    if (l == 0) wred[wid] = lacc;
    __syncthreads();
    if (tid == 0) partial[blk] = wred[0] + wred[1] + wred[2] + wred[3];
}

__global__ void fin_kernel(const double* __restrict__ partial, float* __restrict__ out_loss)
{
    __shared__ double sh[256];
    double s = 0.0;
    for (int i = threadIdx.x; i < F2B; i += 256) s += partial[i];
    sh[threadIdx.x] = s;
    __syncthreads();
    for (int st = 128; st > 0; st >>= 1) {
        if (threadIdx.x < st) sh[threadIdx.x] += sh[threadIdx.x + st];
        __syncthreads();
    }
    if (threadIdx.x == 0)
        out_loss[0] = (float)(1.25 * sh[0] / (double)((long long)NTOT * Cc));
}

// ---------------------------------------------------------------------------
extern "C" void kernel_launch(void* const* d_in, const int* in_sizes, int n_in,
                              void* d_out, int out_size, void* d_ws, size_t ws_size,
                              hipStream_t stream)
{
    const float* z   = (const float*)d_in[0];
    const float* key = (const float*)d_in[1];
    const float* val = (const float*)d_in[2];
    float* out = (float*)d_out;

    // zf16 scratch lives in the z_q_value output region (dead before gather)
    u16* zf16 = (u16*)d_out;

    u16*    ef16    = (u16*)d_ws;                              // 512 KB
    u64*    cand    = (u64*)(ef16 + (size_t)Kc * Cc);          // 12.85 MB
    int*    cnt     = (int*)(cand + (size_t)NTOT * SLOTS);     // 401 KB
    int*    idxw    = cnt + NTOT;                              // 401 KB
    double* partial = (double*)(idxw + NTOT);                  // 25 KB
    float*  esq     = (float*)(partial + F2B);                 // 4 KB
    float*  zsq     = esq + Kc;                                // 401 KB

    hipMemsetAsync(cnt, 0, NTOT * sizeof(int), stream);
    hipLaunchKernelGGL(esq_pw, dim3((Kc + 255) / 256), dim3(256), 0, stream, key, esq);
    hipLaunchKernelGGL(zsq_pw, dim3(NTOT / 256), dim3(256), 0, stream, z, zsq);
    hipLaunchKernelGGL(split_e, dim3((Kc * Cc + 255) / 256), dim3(256), 0, stream, key, ef16);
    hipLaunchKernelGGL(split_z, dim3(NTOT / 64), dim3(256), 0, stream, z, zf16);
    hipLaunchKernelGGL(screen, dim3(SBLK), dim3(256), 0, stream,
                       zf16, ef16, esq, zsq, cand, cnt);
    hipLaunchKernelGGL(resolve, dim3(F1B), dim3(256), 0, stream,
                       z, key, esq, zsq, cand, cnt, out, idxw);
    hipLaunchKernelGGL(gather, dim3(F2B), dim3(256), 0, stream,
                       z, key, val, idxw, out, partial);
    hipLaunchKernelGGL(fin_kernel, dim3(1), dim3(256), 0, stream, partial, out + ZQV + NTOT);
}

// Round 12
// 505.544 us; speedup vs baseline: 1.9852x; 1.3615x over previous
//
#include <hip/hip_runtime.h>
#include <stdint.h>

constexpr int Cc   = 256;
constexpr int Kc   = 1024;
constexpr int NLOC = 16 * 56 * 56;      // 50176
constexpr int NB   = 2;
constexpr int NTOT = NB * NLOC;         // 100352
constexpr long long ZQV = (long long)NB * Cc * NLOC;  // 25690112

// screen tiling: one block = 128 rows x 128 codes, K=256 in 4 chunks of 64
constexpr int SR   = 128;
constexpr int SC   = 128;
constexpr int BK   = 64;
constexpr int NCH  = Cc / BK;           // 4
constexpr int NRT  = NTOT / SR;         // 784 row tiles (= 8 XCDs x 98)
constexpr int NSL  = Kc / SC;           // 8
constexpr int SBLK = NRT * NSL;         // 6272

constexpr int   SLOTS = 16;
constexpr float WIN   = 3e-4f;          // validated (absmax idx = 0 at 3e-4)
constexpr float NEG2S = -0.001953125f;  // -2/1024 (exact descale)

constexpr int F1B = NTOT / 256;         // 392
constexpr int RB  = 32;                 // rows per gather block
constexpr int F2B = NTOT / RB;          // 3136

using f16x8 = __attribute__((ext_vector_type(8))) _Float16;
using f32x4 = __attribute__((ext_vector_type(4))) float;
typedef unsigned long long u64;
typedef unsigned int       u32;
typedef unsigned short     u16;

// ---------------------------------------------------------------------------
// numpy-exact helpers (validated, unchanged)
// ---------------------------------------------------------------------------
__device__ __forceinline__ float sqf(float x) {
    float s = x * x;
    asm("" : "+v"(s));
    return s;
}

template <typename Loader>
__device__ __forceinline__ float pw256_sq(Loader ld)
{
    float half[2];
    #pragma unroll
    for (int h = 0; h < 2; ++h) {
        float r[8];
        #pragma unroll
        for (int j = 0; j < 8; ++j) r[j] = sqf(ld(h * 128 + j));
        #pragma unroll
        for (int i = 8; i < 128; i += 8)
            #pragma unroll
            for (int j = 0; j < 8; ++j) r[j] += sqf(ld(h * 128 + i + j));
        half[h] = ((r[0] + r[1]) + (r[2] + r[3])) + ((r[4] + r[5]) + (r[6] + r[7]));
    }
    return half[0] + half[1];
}

__global__ void esq_pw(const float* __restrict__ key, float* __restrict__ esq)
{
    int k = blockIdx.x * 256 + threadIdx.x;
    if (k < Kc) {
        const float* a = key + (size_t)k * Cc;
        esq[k] = pw256_sq([&](int c) { return a[c]; });
    }
}

__global__ void zsq_pw(const float* __restrict__ z, float* __restrict__ zsq)
{
    int p = blockIdx.x * 256 + threadIdx.x;
    int b = p / NLOC, loc = p - b * NLOC;
    const float* a = z + (size_t)b * Cc * NLOC + loc;
    zsq[p] = pw256_sq([&](int c) { return a[(size_t)c * NLOC]; });
}

__device__ __forceinline__ u16 f16b(float x)
{
    _Float16 h = (_Float16)x;   // v_cvt_f16_f32, RNE
    u16 r;
    __builtin_memcpy(&r, &h, 2);
    return r;
}

// split_e: ef16[k][c] = f16(key[k][c] * 1024)  (exact pow-2 scale)
__global__ void split_e(const float* __restrict__ key, u16* __restrict__ ef16)
{
    int i = blockIdx.x * 256 + threadIdx.x;
    if (i < Kc * Cc) ef16[i] = f16b(key[i] * 1024.0f);
}

// split_z: z [B][C][NLOC] f32 -> zf16 [NTOT][C] f16; optionally zt32 [NTOT][C] f32
__global__ __launch_bounds__(256, 2)
void split_z(const float* __restrict__ z, u16* __restrict__ zf16,
             float* __restrict__ zt32)
{
    __shared__ float t[64][260];
    const int tid = threadIdx.x;
    const int n0  = blockIdx.x * 64;
    const int b   = (n0 >= NLOC) ? 1 : 0;
    const int loc0 = n0 - b * NLOC;
    const float* zb = z + (size_t)b * Cc * NLOC;

    {
        const int n4 = tid & 15;
        #pragma unroll
        for (int it = 0; it < 4; ++it) {
            int c4 = (tid >> 4) + it * 16;
            float4 g0 = *reinterpret_cast<const float4*>(zb + (size_t)(c4 * 4 + 0) * NLOC + loc0 + n4 * 4);
            float4 g1 = *reinterpret_cast<const float4*>(zb + (size_t)(c4 * 4 + 1) * NLOC + loc0 + n4 * 4);
            float4 g2 = *reinterpret_cast<const float4*>(zb + (size_t)(c4 * 4 + 2) * NLOC + loc0 + n4 * 4);
            float4 g3 = *reinterpret_cast<const float4*>(zb + (size_t)(c4 * 4 + 3) * NLOC + loc0 + n4 * 4);
            *reinterpret_cast<float4*>(&t[n4 * 4 + 0][c4 * 4]) = make_float4(g0.x, g1.x, g2.x, g3.x);
            *reinterpret_cast<float4*>(&t[n4 * 4 + 1][c4 * 4]) = make_float4(g0.y, g1.y, g2.y, g3.y);
            *reinterpret_cast<float4*>(&t[n4 * 4 + 2][c4 * 4]) = make_float4(g0.z, g1.z, g2.z, g3.z);
            *reinterpret_cast<float4*>(&t[n4 * 4 + 3][c4 * 4]) = make_float4(g0.w, g1.w, g2.w, g3.w);
        }
    }
    __syncthreads();
    {
        const int row2 = tid >> 5;
        const int ch   = tid & 31;
        #pragma unroll
        for (int rg = 0; rg < 8; ++rg) {
            int row = rg * 8 + row2;
            float4 f0 = *reinterpret_cast<const float4*>(&t[row][ch * 8]);
            float4 f1 = *reinterpret_cast<const float4*>(&t[row][ch * 8 + 4]);
            float xs[8] = {f0.x, f0.y, f0.z, f0.w, f1.x, f1.y, f1.z, f1.w};
            u32 hp[4];
            #pragma unroll
            for (int j = 0; j < 4; ++j)
                hp[j] = (u32)f16b(xs[2 * j]) | ((u32)f16b(xs[2 * j + 1]) << 16);
            size_t o = ((size_t)(n0 + row)) * Cc + ch * 8;
            *reinterpret_cast<uint4*>(zf16 + o) = make_uint4(hp[0], hp[1], hp[2], hp[3]);
            if (zt32) {
                *reinterpret_cast<float4*>(zt32 + o)     = f0;   // bit-exact f32 copies
                *reinterpret_cast<float4*>(zt32 + o + 4) = f1;
            }
        }
    }
}

// global -> LDS direct, 16B/lane (dest = uniform base + lane*16)
__device__ __forceinline__ void gload16(const u16* g, u16* lds)
{
    __builtin_amdgcn_global_load_lds(
        (const __attribute__((address_space(1))) u32*)g,
        (__attribute__((address_space(3))) u32*)lds, 16, 0, 0);
}

// ---------------------------------------------------------------------------
// screen: f16 MFMA GEMM, 128x128 tile, BK=64 — logic unchanged (validated);
// NEW: XCD-aware block remap (the 8 slice-blocks of a row-tile share one XCD's
// L2 -> A-panel fetched once per XCD instead of 8x across XCDs).
// ---------------------------------------------------------------------------
__global__ __launch_bounds__(256, 4)
void screen(const u16* __restrict__ zf16, const u16* __restrict__ ef16,
            const float* __restrict__ esq, const float* __restrict__ zsq,
            u64* __restrict__ cand, int* __restrict__ cnt)
{
    __shared__ u16  A_lds[SR * BK];    // 16 KB
    __shared__ u16  B_lds[SC * BK];    // 16 KB
    __shared__ u64  gm[2][SR];         // 2 KB
    __shared__ float esq_s[SC];
    __shared__ float zsq_s[SR];

    const int tid = threadIdx.x;
    const int bid = blockIdx.x;
    // XCD grouping: xcd = bid&7 owns row-tiles [xcd*98, (xcd+1)*98); its 8
    // slice-blocks of one row-tile are dispatched consecutively on that XCD.
    const int q   = bid >> 3;
    const int rt  = (bid & 7) * (NRT / 8) + (q >> 3);
    const int r0  = rt * SR;
    const int k0  = (q & 7) * SC;
    const int wid = tid >> 6, l = tid & 63;
    const int wr  = wid >> 1, wc = wid & 1;

    for (int i = tid; i < SC; i += 256) esq_s[i] = esq[k0 + i];
    for (int i = tid; i < SR; i += 256) zsq_s[i] = zsq[r0 + i];

    f32x4 acc[4][4];
    #pragma unroll
    for (int i = 0; i < 4; ++i)
        #pragma unroll
        for (int j = 0; j < 4; ++j)
            acc[i][j] = f32x4{0.f, 0.f, 0.f, 0.f};

    for (int ch = 0; ch < NCH; ++ch) {
        __syncthreads();
        {
            const int lr = l >> 3;
            #pragma unroll
            for (int t = 0; t < 4; ++t) {
                int rowb = wid * 32 + t * 8;
                int row  = rowb + lr;
                int g    = (l & 7) ^ (row & 7);
                gload16(zf16 + (size_t)(r0 + row) * Cc + ch * BK + g * 8,
                        A_lds + rowb * BK);
                gload16(ef16 + (size_t)(k0 + row) * Cc + ch * BK + g * 8,
                        B_lds + rowb * BK);
            }
        }
        __syncthreads();

        #pragma unroll
        for (int kk = 0; kk < 2; ++kk) {
            f16x8 af[4], bf[4];
            const int G = kk * 4 + (l >> 4);
            #pragma unroll
            for (int i = 0; i < 4; ++i) {
                int row = wr * 64 + i * 16 + (l & 15);
                int pg  = G ^ (row & 7);
                af[i] = *reinterpret_cast<const f16x8*>(&A_lds[row * BK + pg * 8]);
            }
            #pragma unroll
            for (int j = 0; j < 4; ++j) {
                int col = wc * 64 + j * 16 + (l & 15);
                int pg  = G ^ (col & 7);
                bf[j] = *reinterpret_cast<const f16x8*>(&B_lds[col * BK + pg * 8]);
            }
            #pragma unroll
            for (int i = 0; i < 4; ++i)
                #pragma unroll
                for (int j = 0; j < 4; ++j)
                    acc[i][j] = __builtin_amdgcn_mfma_f32_16x16x32_f16(
                        af[i], bf[j], acc[i][j], 0, 0, 0);
        }
    }

    #pragma unroll
    for (int i = 0; i < 4; ++i) {
        #pragma unroll
        for (int r = 0; r < 4; ++r) {
            int rloc = wr * 64 + i * 16 + ((l >> 4) << 2) + r;
            float zq = zsq_s[rloc];
            u64 mn = 0xFFFFFFFFFFFFFFFFull;
            #pragma unroll
            for (int j = 0; j < 4; ++j) {
                int cl = wc * 64 + j * 16 + (l & 15);
                float t = zq + esq_s[cl];
                float d = fmaf(NEG2S, acc[i][j][r], t);
                u64 pk = ((u64)__float_as_uint(d) << 32) | (u32)(k0 + cl);
                mn = pk < mn ? pk : mn;
            }
            #pragma unroll
            for (int m = 1; m < 16; m <<= 1) {
                u64 o = __shfl_xor(mn, m, 64);
                mn = o < mn ? o : mn;
            }
            if ((l & 15) == 0) gm[wc][rloc] = mn;
        }
    }
    __syncthreads();

    #pragma unroll
    for (int i = 0; i < 4; ++i) {
        #pragma unroll
        for (int r = 0; r < 4; ++r) {
            int rloc = wr * 64 + i * 16 + ((l >> 4) << 2) + r;
            u64 m0 = gm[0][rloc], m1 = gm[1][rloc];
            u64 sm = m0 < m1 ? m0 : m1;
            float thr = __uint_as_float((u32)(sm >> 32)) + WIN;
            float zq = zsq_s[rloc];
            int rg = r0 + rloc;
            #pragma unroll
            for (int j = 0; j < 4; ++j) {
                int cl = wc * 64 + j * 16 + (l & 15);
                float t = zq + esq_s[cl];
                float d = fmaf(NEG2S, acc[i][j][r], t);
                if (d <= thr) {
                    int slot = atomicAdd(&cnt[rg], 1);
                    if (slot < SLOTS)
                        cand[(size_t)rg * SLOTS + slot] =
                            ((u64)__float_as_uint(d) << 32) | (u32)(k0 + cl);
                }
            }
        }
    }
}

// ---------------------------------------------------------------------------
// resolve_pick: thread per row; pick best candidate; push ambiguous/overflow
// rows to a worklist (no z reads here).
// ---------------------------------------------------------------------------
__global__ __launch_bounds__(256)
void resolve_pick(const u64* __restrict__ cand, const int* __restrict__ cnt,
                  int* __restrict__ idxw, float* __restrict__ out,
                  int* __restrict__ wl, int* __restrict__ wcount)
{
    const int p = blockIdx.x * 256 + threadIdx.x;
    const int c = cnt[p];
    const int n = (c < SLOTS) ? c : SLOTS;
    u64 best = 0xFFFFFFFFFFFFFFFFull;
    for (int s = 0; s < n; ++s) {
        u64 v = cand[(size_t)p * SLOTS + s];
        if (v < best) best = v;
    }
    const float db = __uint_as_float((u32)(best >> 32));

    bool needs = (c > SLOTS);
    if (!needs) {
        int namb = 0;
        for (int s = 0; s < n; ++s) {
            float dv = __uint_as_float((u32)(cand[(size_t)p * SLOTS + s] >> 32));
            namb += (dv <= db + WIN) ? 1 : 0;
        }
        needs = (namb > 1);
    }
    if (needs) wl[atomicAdd(wcount, 1)] = p;

    idxw[p] = (int)(u32)best;          // final for unambiguous rows
    out[ZQV + p] = (float)(u32)best;
}

// ---------------------------------------------------------------------------
// rescore: np-exact re-evaluation of worklist rows using contiguous zt32 rows.
// ---------------------------------------------------------------------------
__global__ __launch_bounds__(256)
void rescore(const float* __restrict__ zt32, const float* __restrict__ key,
             const float* __restrict__ esq, const float* __restrict__ zsq,
             const u64* __restrict__ cand, const int* __restrict__ cnt,
             const int* __restrict__ wcount, const int* __restrict__ wl,
             int* __restrict__ idxw, float* __restrict__ out)
{
    const int i = blockIdx.x * 256 + threadIdx.x;
    if (i >= *wcount) return;
    const int p = wl[i];
    const float* zr = zt32 + (size_t)p * Cc;   // bit-exact f32 z row
    const float zq = zsq[p];
    const int c = cnt[p];
    u64 bb = 0xFFFFFFFFFFFFFFFFull;

    if (c > SLOTS) {
        // overflow backstop: full np-exact scan
        for (int k = 0; k < Kc; ++k) {
            const float* kr = key + (size_t)k * Cc;
            float m = 0.f;
            for (int cc = 0; cc < Cc; ++cc)
                m = fmaf(zr[cc], kr[cc], m);
            float d = fmaf(-2.0f, m, zq + esq[k]);
            u64 pk = ((u64)__float_as_uint(d) << 32) | (u32)k;
            if (pk < bb) bb = pk;
        }
    } else {
        u64 best = 0xFFFFFFFFFFFFFFFFull;
        for (int s = 0; s < c; ++s) {
            u64 v = cand[(size_t)p * SLOTS + s];
            if (v < best) best = v;
        }
        const float db = __uint_as_float((u32)(best >> 32));
        for (int s = 0; s < c; ++s) {
            u64 v = cand[(size_t)p * SLOTS + s];
            float dv = __uint_as_float((u32)(v >> 32));
            if (dv <= db + WIN) {
                int k = (int)(u32)v;
                const float* kr = key + (size_t)k * Cc;
                float m = 0.f;
                for (int cc = 0; cc < Cc; ++cc)
                    m = fmaf(zr[cc], kr[cc], m);
                float d = fmaf(-2.0f, m, zq + esq[k]);
                u64 pk = ((u64)__float_as_uint(d) << 32) | (u32)k;
                if (pk < bb) bb = pk;
            }
        }
    }
    idxw[p] = (int)(u32)bb;
    out[ZQV + p] = (float)(u32)bb;
}

// ---------------------------------------------------------------------------
// resolve_fallback: monolithic path (strided z reads) if ws too small for zt32
// ---------------------------------------------------------------------------
__global__ __launch_bounds__(256)
void resolve_fallback(const float* __restrict__ z, const float* __restrict__ key,
                      const float* __restrict__ esq, const float* __restrict__ zsq,
                      const u64* __restrict__ cand, const int* __restrict__ cnt,
                      float* __restrict__ out, int* __restrict__ idxw)
{
    const int p   = blockIdx.x * 256 + threadIdx.x;
    const int b   = (p >= NLOC) ? 1 : 0;
    const int loc = p - b * NLOC;
    const float* zb = z + (size_t)b * Cc * NLOC;

    const int c = cnt[p];
    const int n = (c < SLOTS) ? c : SLOTS;
    u64 best = 0xFFFFFFFFFFFFFFFFull;
    for (int s = 0; s < n; ++s) {
        u64 v = cand[(size_t)p * SLOTS + s];
        if (v < best) best = v;
    }
    int kbest = (int)(u32)best;
    const float db = __uint_as_float((u32)(best >> 32));

    if (c > SLOTS) {
        u64 bb = 0xFFFFFFFFFFFFFFFFull;
        for (int k = 0; k < Kc; ++k) {
            const float* kr = key + (size_t)k * Cc;
            float m = 0.f;
            for (int cc = 0; cc < Cc; ++cc)
                m = fmaf(zb[(size_t)cc * NLOC + loc], kr[cc], m);
            float d = fmaf(-2.0f, m, zsq[p] + esq[k]);
            u64 pk = ((u64)__float_as_uint(d) << 32) | (u32)k;
            if (pk < bb) bb = pk;
        }
        kbest = (int)(u32)bb;
    } else {
        int namb = 0;
        for (int s = 0; s < n; ++s) {
            float dv = __uint_as_float((u32)(cand[(size_t)p * SLOTS + s] >> 32));
            namb += (dv <= db + WIN) ? 1 : 0;
        }
        if (namb > 1) {
            u64 bb = 0xFFFFFFFFFFFFFFFFull;
            for (int s = 0; s < n; ++s) {
                u64 v = cand[(size_t)p * SLOTS + s];
                float dv = __uint_as_float((u32)(v >> 32));
                if (dv <= db + WIN) {
                    int k = (int)(u32)v;
                    const float* kr = key + (size_t)k * Cc;
                    float m = 0.f;
                    for (int cc = 0; cc < Cc; ++cc)
                        m = fmaf(zb[(size_t)cc * NLOC + loc], kr[cc], m);
                    float d = fmaf(-2.0f, m, zsq[p] + esq[k]);
                    u64 pk = ((u64)__float_as_uint(d) << 32) | (u32)k;
                    if (pk < bb) bb = pk;
                }
            }
            kbest = (int)(u32)bb;
        }
    }
    idxw[p] = kbest;
    out[ZQV + p] = (float)kbest;
}

// ---------------------------------------------------------------------------
// gather: 32 rows/block; FIX: cc ranges distributed across waves (R11 bug:
// all 4 waves covered the full tile -> loss counted 4x).
// ---------------------------------------------------------------------------
__global__ __launch_bounds__(256)
void gather(const float* __restrict__ z, const float* __restrict__ key,
            const float* __restrict__ val, const int* __restrict__ idxw,
            float* __restrict__ out, double* __restrict__ partial)
{
    __shared__ float rowbuf[RB][261];
    __shared__ int   idx_sh[RB];
    __shared__ double wred[4];
    const int tid = threadIdx.x, blk = blockIdx.x;
    const int wid = tid >> 6, l = tid & 63;
    const int p0  = blk * RB;
    const int b   = (p0 >= NLOC) ? 1 : 0;
    const int loc0 = p0 - b * NLOC;
    const float* zb = z + (size_t)b * Cc * NLOC;

    if (tid < RB) idx_sh[tid] = idxw[p0 + tid];
    __syncthreads();

    #pragma unroll
    for (int i = 0; i < RB / 4; ++i) {
        int row = wid * (RB / 4) + i;
        float4 v = *reinterpret_cast<const float4*>(val + (size_t)idx_sh[row] * Cc + l * 4);
        *reinterpret_cast<float4*>(&rowbuf[row][l * 4]) = v;
    }
    __syncthreads();

    // write z_q_value: wave wid covers cc in [wid*64, wid*64+64)
    const int nq = l & 7;
    #pragma unroll
    for (int it = 0; it < 8; ++it) {
        int cc = (l >> 3) + 8 * it + 64 * wid;
        float4 v = make_float4(rowbuf[nq * 4 + 0][cc], rowbuf[nq * 4 + 1][cc],
                               rowbuf[nq * 4 + 2][cc], rowbuf[nq * 4 + 3][cc]);
        *reinterpret_cast<float4*>(
            out + ((size_t)b * Cc + cc) * NLOC + loc0 + nq * 4) = v;
    }
    __syncthreads();

    #pragma unroll
    for (int i = 0; i < RB / 4; ++i) {
        int row = wid * (RB / 4) + i;
        float4 v = *reinterpret_cast<const float4*>(key + (size_t)idx_sh[row] * Cc + l * 4);
        *reinterpret_cast<float4*>(&rowbuf[row][l * 4]) = v;
    }
    __syncthreads();

    // f64 loss: wave-distinct cc ranges (bugfix)
    double lacc = 0.0;
    #pragma unroll
    for (int it = 0; it < 8; ++it) {
        int cc = (l >> 3) + 8 * it + 64 * wid;
        float4 zv = *reinterpret_cast<const float4*>(
            zb + (size_t)cc * NLOC + loc0 + nq * 4);
        double d0 = (double)rowbuf[nq * 4 + 0][cc] - (double)zv.x;
        double d1 = (double)rowbuf[nq * 4 + 1][cc] - (double)zv.y;
        double d2 = (double)rowbuf[nq * 4 + 2][cc] - (double)zv.z;
        double d3 = (double)rowbuf[nq * 4 + 3][cc] - (double)zv.w;
        lacc = fma(d0, d0, lacc); lacc = fma(d1, d1, lacc);
        lacc = fma(d2, d2, lacc); lacc = fma(d3, d3, lacc);
    }
    for (int off = 32; off > 0; off >>= 1) lacc += __shfl_down(lacc, off);
    if (l == 0) wred[wid] = lacc;
    __syncthreads();
    if (tid == 0) partial[blk] = wred[0] + wred[1] + wred[2] + wred[3];
}

__global__ void fin_kernel(const double* __restrict__ partial, float* __restrict__ out_loss)
{
    __shared__ double sh[256];
    double s = 0.0;
    for (int i = threadIdx.x; i < F2B; i += 256) s += partial[i];
    sh[threadIdx.x] = s;
    __syncthreads();
    for (int st = 128; st > 0; st >>= 1) {
        if (threadIdx.x < st) sh[threadIdx.x] += sh[threadIdx.x + st];
        __syncthreads();
    }
    if (threadIdx.x == 0)
        out_loss[0] = (float)(1.25 * sh[0] / (double)((long long)NTOT * Cc));
}

// ---------------------------------------------------------------------------
extern "C" void kernel_launch(void* const* d_in, const int* in_sizes, int n_in,
                              void* d_out, int out_size, void* d_ws, size_t ws_size,
                              hipStream_t stream)
{
    const float* z   = (const float*)d_in[0];
    const float* key = (const float*)d_in[1];
    const float* val = (const float*)d_in[2];
    float* out = (float*)d_out;

    // zf16 scratch lives in the z_q_value output region (dead before gather)
    u16* zf16 = (u16*)d_out;

    char* w = (char*)d_ws;
    u16*    ef16    = (u16*)w;                 w += (size_t)Kc * Cc * 2;        // 512 KB
    u64*    cand    = (u64*)w;                 w += (size_t)NTOT * SLOTS * 8;   // 12.85 MB
    int*    cnt     = (int*)w;                 w += (size_t)NTOT * 4;           // 401 KB
    int*    wcount  = (int*)w;                 w += 16;
    int*    idxw    = (int*)w;                 w += (size_t)NTOT * 4;
    int*    wl      = (int*)w;                 w += (size_t)NTOT * 4;
    double* partial = (double*)w;              w += (size_t)F2B * 8;
    float*  esq     = (float*)w;               w += (size_t)Kc * 4;
    float*  zsq     = (float*)w;               w += (size_t)NTOT * 4;
    float*  zt32    = (float*)w;
    size_t  need_big = (size_t)(w - (char*)d_ws) + (size_t)NTOT * Cc * 4;
    const bool big = ws_size >= need_big;

    hipMemsetAsync(cnt, 0, (size_t)NTOT * 4 + 16, stream);  // cnt + wcount
    hipLaunchKernelGGL(esq_pw, dim3((Kc + 255) / 256), dim3(256), 0, stream, key, esq);
    hipLaunchKernelGGL(zsq_pw, dim3(NTOT / 256), dim3(256), 0, stream, z, zsq);
    hipLaunchKernelGGL(split_e, dim3((Kc * Cc + 255) / 256), dim3(256), 0, stream, key, ef16);
    hipLaunchKernelGGL(split_z, dim3(NTOT / 64), dim3(256), 0, stream, z, zf16,
                       big ? zt32 : (float*)nullptr);
    hipLaunchKernelGGL(screen, dim3(SBLK), dim3(256), 0, stream,
                       zf16, ef16, esq, zsq, cand, cnt);
    if (big) {
        hipLaunchKernelGGL(resolve_pick, dim3(F1B), dim3(256), 0, stream,
                           cand, cnt, idxw, out, wl, wcount);
        hipLaunchKernelGGL(rescore, dim3(F1B), dim3(256), 0, stream,
                           zt32, key, esq, zsq, cand, cnt, wcount, wl, idxw, out);
    } else {
        hipLaunchKernelGGL(resolve_fallback, dim3(F1B), dim3(256), 0, stream,
                           z, key, esq, zsq, cand, cnt, out, idxw);
    }
    hipLaunchKernelGGL(gather, dim3(F2B), dim3(256), 0, stream,
                       z, key, val, idxw, out, partial);
    hipLaunchKernelGGL(fin_kernel, dim3(1), dim3(256), 0, stream, partial, out + ZQV + NTOT);
}

// Round 13
// 483.764 us; speedup vs baseline: 2.0745x; 1.0450x over previous
//
#include <hip/hip_runtime.h>
#include <stdint.h>

constexpr int Cc   = 256;
constexpr int Kc   = 1024;
constexpr int NLOC = 16 * 56 * 56;      // 50176
constexpr int NB   = 2;
constexpr int NTOT = NB * NLOC;         // 100352
constexpr long long ZQV = (long long)NB * Cc * NLOC;  // 25690112

// screen tiling: one block = 128 rows x 128 codes, K=256 in 4 chunks of 64
constexpr int SR   = 128;
constexpr int SC   = 128;
constexpr int BK   = 64;
constexpr int NCH  = Cc / BK;           // 4
constexpr int NRT  = NTOT / SR;         // 784 row tiles (= 8 XCDs x 98)
constexpr int NSL  = Kc / SC;           // 8
constexpr int SBLK = NRT * NSL;         // 6272

constexpr int   SLOTS = 16;
constexpr float WIN   = 3e-4f;          // validated (absmax idx = 0 at 3e-4)
constexpr float NEG2S = -0.001953125f;  // -2/1024 (exact descale)

constexpr int F1B = NTOT / 256;         // 392
constexpr int RB  = 32;                 // rows per gather block
constexpr int F2B = NTOT / RB;          // 3136

using f16x8 = __attribute__((ext_vector_type(8))) _Float16;
using f32x4 = __attribute__((ext_vector_type(4))) float;
typedef unsigned long long u64;
typedef unsigned int       u32;
typedef unsigned short     u16;

// ---------------------------------------------------------------------------
// numpy-exact helpers (validated, unchanged)
// ---------------------------------------------------------------------------
__device__ __forceinline__ float sqf(float x) {
    float s = x * x;
    asm("" : "+v"(s));
    return s;
}

template <typename Loader>
__device__ __forceinline__ float pw256_sq(Loader ld)
{
    float half[2];
    #pragma unroll
    for (int h = 0; h < 2; ++h) {
        float r[8];
        #pragma unroll
        for (int j = 0; j < 8; ++j) r[j] = sqf(ld(h * 128 + j));
        #pragma unroll
        for (int i = 8; i < 128; i += 8)
            #pragma unroll
            for (int j = 0; j < 8; ++j) r[j] += sqf(ld(h * 128 + i + j));
        half[h] = ((r[0] + r[1]) + (r[2] + r[3])) + ((r[4] + r[5]) + (r[6] + r[7]));
    }
    return half[0] + half[1];
}

__global__ void esq_pw(const float* __restrict__ key, float* __restrict__ esq)
{
    int k = blockIdx.x * 256 + threadIdx.x;
    if (k < Kc) {
        const float* a = key + (size_t)k * Cc;
        esq[k] = pw256_sq([&](int c) { return a[c]; });
    }
}

__device__ __forceinline__ u16 f16b(float x)
{
    _Float16 h = (_Float16)x;   // v_cvt_f16_f32, RNE
    u16 r;
    __builtin_memcpy(&r, &h, 2);
    return r;
}

// split_e: ef16[k][c] = f16(key[k][c] * 1024)  (exact pow-2 scale)
__global__ void split_e(const float* __restrict__ key, u16* __restrict__ ef16)
{
    int i = blockIdx.x * 256 + threadIdx.x;
    if (i < Kc * Cc) ef16[i] = f16b(key[i] * 1024.0f);
}

// split_z: z [B][C][NLOC] f32 -> zf16 [NTOT][C] f16 (+ zt32 f32 copy, + zsq)
// zsq fused: rows sit in LDS; numpy-pairwise sum over bit-exact copies.
__global__ __launch_bounds__(256, 2)
void split_z(const float* __restrict__ z, u16* __restrict__ zf16,
             float* __restrict__ zt32, float* __restrict__ zsq)
{
    __shared__ float t[64][260];
    const int tid = threadIdx.x;
    const int n0  = blockIdx.x * 64;
    const int b   = (n0 >= NLOC) ? 1 : 0;
    const int loc0 = n0 - b * NLOC;
    const float* zb = z + (size_t)b * Cc * NLOC;

    {
        const int n4 = tid & 15;
        #pragma unroll
        for (int it = 0; it < 4; ++it) {
            int c4 = (tid >> 4) + it * 16;
            float4 g0 = *reinterpret_cast<const float4*>(zb + (size_t)(c4 * 4 + 0) * NLOC + loc0 + n4 * 4);
            float4 g1 = *reinterpret_cast<const float4*>(zb + (size_t)(c4 * 4 + 1) * NLOC + loc0 + n4 * 4);
            float4 g2 = *reinterpret_cast<const float4*>(zb + (size_t)(c4 * 4 + 2) * NLOC + loc0 + n4 * 4);
            float4 g3 = *reinterpret_cast<const float4*>(zb + (size_t)(c4 * 4 + 3) * NLOC + loc0 + n4 * 4);
            *reinterpret_cast<float4*>(&t[n4 * 4 + 0][c4 * 4]) = make_float4(g0.x, g1.x, g2.x, g3.x);
            *reinterpret_cast<float4*>(&t[n4 * 4 + 1][c4 * 4]) = make_float4(g0.y, g1.y, g2.y, g3.y);
            *reinterpret_cast<float4*>(&t[n4 * 4 + 2][c4 * 4]) = make_float4(g0.z, g1.z, g2.z, g3.z);
            *reinterpret_cast<float4*>(&t[n4 * 4 + 3][c4 * 4]) = make_float4(g0.w, g1.w, g2.w, g3.w);
        }
    }
    __syncthreads();
    {
        const int row2 = tid >> 5;
        const int ch   = tid & 31;
        #pragma unroll
        for (int rg = 0; rg < 8; ++rg) {
            int row = rg * 8 + row2;
            float4 f0 = *reinterpret_cast<const float4*>(&t[row][ch * 8]);
            float4 f1 = *reinterpret_cast<const float4*>(&t[row][ch * 8 + 4]);
            float xs[8] = {f0.x, f0.y, f0.z, f0.w, f1.x, f1.y, f1.z, f1.w};
            u32 hp[4];
            #pragma unroll
            for (int j = 0; j < 4; ++j)
                hp[j] = (u32)f16b(xs[2 * j]) | ((u32)f16b(xs[2 * j + 1]) << 16);
            size_t o = ((size_t)(n0 + row)) * Cc + ch * 8;
            *reinterpret_cast<uint4*>(zf16 + o) = make_uint4(hp[0], hp[1], hp[2], hp[3]);
            if (zt32) {
                *reinterpret_cast<float4*>(zt32 + o)     = f0;   // bit-exact f32 copies
                *reinterpret_cast<float4*>(zt32 + o + 4) = f1;
            }
        }
    }
    // fused zsq: numpy-pairwise over the LDS row (bit-exact copies)
    if (tid < 64)
        zsq[n0 + tid] = pw256_sq([&](int c) { return t[tid][c]; });
}

// global -> LDS direct, 16B/lane (dest = uniform base + lane*16)
__device__ __forceinline__ void gload16(const u16* g, u16* lds)
{
    __builtin_amdgcn_global_load_lds(
        (const __attribute__((address_space(1))) u32*)g,
        (__attribute__((address_space(3))) u32*)lds, 16, 0, 0);
}

// ---------------------------------------------------------------------------
// screen: f16 MFMA GEMM, 128x128 tile, BK=64, XCD-aware block remap.
// NEW: stage-early double-buffer (T3 minimal 2-phase): issue chunk ch+1's
// global_load_lds into buf^1 BEFORE computing buf; ONE barrier per chunk ->
// HBM latency hides under ds_read+MFMA. Epilogue slice-min in f32.
// ---------------------------------------------------------------------------
__global__ __launch_bounds__(256, 2)
void screen(const u16* __restrict__ zf16, const u16* __restrict__ ef16,
            const float* __restrict__ esq, const float* __restrict__ zsq,
            u64* __restrict__ cand, int* __restrict__ cnt)
{
    __shared__ u16  A_lds[2][SR * BK];   // 2 x 16 KB
    __shared__ u16  B_lds[2][SC * BK];   // 2 x 16 KB
    __shared__ float gm[2][SR];          // 1 KB (f32 slice-min)
    __shared__ float esq_s[SC];
    __shared__ float zsq_s[SR];

    const int tid = threadIdx.x;
    const int bid = blockIdx.x;
    // XCD grouping: xcd = bid&7 owns row-tiles [xcd*98, (xcd+1)*98)
    const int q   = bid >> 3;
    const int rt  = (bid & 7) * (NRT / 8) + (q >> 3);
    const int r0  = rt * SR;
    const int k0  = (q & 7) * SC;
    const int wid = tid >> 6, l = tid & 63;
    const int wr  = wid >> 1, wc = wid & 1;

    auto stage = [&](int buf, int ch) {
        const int lr = l >> 3;
        #pragma unroll
        for (int t = 0; t < 4; ++t) {
            int rowb = wid * 32 + t * 8;
            int row  = rowb + lr;
            int g    = (l & 7) ^ (row & 7);
            gload16(zf16 + (size_t)(r0 + row) * Cc + ch * BK + g * 8,
                    &A_lds[buf][rowb * BK]);
            gload16(ef16 + (size_t)(k0 + row) * Cc + ch * BK + g * 8,
                    &B_lds[buf][rowb * BK]);
        }
    };

    // prologue: stage chunk 0 + esq/zsq
    stage(0, 0);
    for (int i = tid; i < SC; i += 256) esq_s[i] = esq[k0 + i];
    for (int i = tid; i < SR; i += 256) zsq_s[i] = zsq[r0 + i];

    f32x4 acc[4][4];
    #pragma unroll
    for (int i = 0; i < 4; ++i)
        #pragma unroll
        for (int j = 0; j < 4; ++j)
            acc[i][j] = f32x4{0.f, 0.f, 0.f, 0.f};

    __syncthreads();   // drains vmcnt: A0/B0 + esq_s/zsq_s ready

    int cur = 0;
    for (int ch = 0; ch < NCH; ++ch) {
        if (ch + 1 < NCH) stage(cur ^ 1, ch + 1);   // prefetch under compute

        const u16* Ab = &A_lds[cur][0];
        const u16* Bb = &B_lds[cur][0];
        #pragma unroll
        for (int kk = 0; kk < 2; ++kk) {
            f16x8 af[4], bf[4];
            const int G = kk * 4 + (l >> 4);
            #pragma unroll
            for (int i = 0; i < 4; ++i) {
                int row = wr * 64 + i * 16 + (l & 15);
                int pg  = G ^ (row & 7);
                af[i] = *reinterpret_cast<const f16x8*>(&Ab[row * BK + pg * 8]);
            }
            #pragma unroll
            for (int j = 0; j < 4; ++j) {
                int col = wc * 64 + j * 16 + (l & 15);
                int pg  = G ^ (col & 7);
                bf[j] = *reinterpret_cast<const f16x8*>(&Bb[col * BK + pg * 8]);
            }
            #pragma unroll
            for (int i = 0; i < 4; ++i)
                #pragma unroll
                for (int j = 0; j < 4; ++j)
                    acc[i][j] = __builtin_amdgcn_mfma_f32_16x16x32_f16(
                        af[i], bf[j], acc[i][j], 0, 0, 0);
        }

        __syncthreads();   // drains vmcnt (prefetch landed); buf swap safe
        cur ^= 1;
    }

    // ---- epilogue pass 1: f32 slice-min per row ----
    #pragma unroll
    for (int i = 0; i < 4; ++i) {
        #pragma unroll
        for (int r = 0; r < 4; ++r) {
            int rloc = wr * 64 + i * 16 + ((l >> 4) << 2) + r;
            float zq = zsq_s[rloc];
            float mn = 3.4e38f;
            #pragma unroll
            for (int j = 0; j < 4; ++j) {
                int cl = wc * 64 + j * 16 + (l & 15);
                float d = fmaf(NEG2S, acc[i][j][r], zq + esq_s[cl]);
                mn = fminf(mn, d);
            }
            #pragma unroll
            for (int m = 1; m < 16; m <<= 1)
                mn = fminf(mn, __shfl_xor(mn, m, 64));
            if ((l & 15) == 0) gm[wc][rloc] = mn;
        }
    }
    __syncthreads();

    // ---- epilogue pass 2: window emission ----
    #pragma unroll
    for (int i = 0; i < 4; ++i) {
        #pragma unroll
        for (int r = 0; r < 4; ++r) {
            int rloc = wr * 64 + i * 16 + ((l >> 4) << 2) + r;
            float thr = fminf(gm[0][rloc], gm[1][rloc]) + WIN;
            float zq = zsq_s[rloc];
            int rg = r0 + rloc;
            #pragma unroll
            for (int j = 0; j < 4; ++j) {
                int cl = wc * 64 + j * 16 + (l & 15);
                float d = fmaf(NEG2S, acc[i][j][r], zq + esq_s[cl]);
                if (d <= thr) {
                    int slot = atomicAdd(&cnt[rg], 1);
                    if (slot < SLOTS)
                        cand[(size_t)rg * SLOTS + slot] =
                            ((u64)__float_as_uint(d) << 32) | (u32)(k0 + cl);
                }
            }
        }
    }
}

// ---------------------------------------------------------------------------
// resolve_pick: thread per row; pick best candidate; push ambiguous/overflow
// rows to a worklist (no z reads here).
// ---------------------------------------------------------------------------
__global__ __launch_bounds__(256)
void resolve_pick(const u64* __restrict__ cand, const int* __restrict__ cnt,
                  int* __restrict__ idxw, float* __restrict__ out,
                  int* __restrict__ wl, int* __restrict__ wcount)
{
    const int p = blockIdx.x * 256 + threadIdx.x;
    const int c = cnt[p];
    const int n = (c < SLOTS) ? c : SLOTS;
    u64 best = 0xFFFFFFFFFFFFFFFFull;
    for (int s = 0; s < n; ++s) {
        u64 v = cand[(size_t)p * SLOTS + s];
        if (v < best) best = v;
    }
    const float db = __uint_as_float((u32)(best >> 32));

    bool needs = (c > SLOTS);
    if (!needs) {
        int namb = 0;
        for (int s = 0; s < n; ++s) {
            float dv = __uint_as_float((u32)(cand[(size_t)p * SLOTS + s] >> 32));
            namb += (dv <= db + WIN) ? 1 : 0;
        }
        needs = (namb > 1);
    }
    if (needs) wl[atomicAdd(wcount, 1)] = p;

    idxw[p] = (int)(u32)best;          // final for unambiguous rows
    out[ZQV + p] = (float)(u32)best;
}

// ---------------------------------------------------------------------------
// rescore: np-exact re-evaluation of worklist rows using contiguous zt32 rows.
// ---------------------------------------------------------------------------
__global__ __launch_bounds__(256)
void rescore(const float* __restrict__ zt32, const float* __restrict__ key,
             const float* __restrict__ esq, const float* __restrict__ zsq,
             const u64* __restrict__ cand, const int* __restrict__ cnt,
             const int* __restrict__ wcount, const int* __restrict__ wl,
             int* __restrict__ idxw, float* __restrict__ out)
{
    const int i = blockIdx.x * 256 + threadIdx.x;
    if (i >= *wcount) return;
    const int p = wl[i];
    const float* zr = zt32 + (size_t)p * Cc;   // bit-exact f32 z row
    const float zq = zsq[p];
    const int c = cnt[p];
    u64 bb = 0xFFFFFFFFFFFFFFFFull;

    if (c > SLOTS) {
        // overflow backstop: full np-exact scan
        for (int k = 0; k < Kc; ++k) {
            const float* kr = key + (size_t)k * Cc;
            float m = 0.f;
            for (int cc = 0; cc < Cc; ++cc)
                m = fmaf(zr[cc], kr[cc], m);
            float d = fmaf(-2.0f, m, zq + esq[k]);
            u64 pk = ((u64)__float_as_uint(d) << 32) | (u32)k;
            if (pk < bb) bb = pk;
        }
    } else {
        u64 best = 0xFFFFFFFFFFFFFFFFull;
        for (int s = 0; s < c; ++s) {
            u64 v = cand[(size_t)p * SLOTS + s];
            if (v < best) best = v;
        }
        const float db = __uint_as_float((u32)(best >> 32));
        for (int s = 0; s < c; ++s) {
            u64 v = cand[(size_t)p * SLOTS + s];
            float dv = __uint_as_float((u32)(v >> 32));
            if (dv <= db + WIN) {
                int k = (int)(u32)v;
                const float* kr = key + (size_t)k * Cc;
                float m = 0.f;
                for (int cc = 0; cc < Cc; ++cc)
                    m = fmaf(zr[cc], kr[cc], m);
                float d = fmaf(-2.0f, m, zq + esq[k]);
                u64 pk = ((u64)__float_as_uint(d) << 32) | (u32)k;
                if (pk < bb) bb = pk;
            }
        }
    }
    idxw[p] = (int)(u32)bb;
    out[ZQV + p] = (float)(u32)bb;
}

// ---------------------------------------------------------------------------
// resolve_fallback: monolithic path (strided z reads) if ws too small for zt32
// ---------------------------------------------------------------------------
__global__ __launch_bounds__(256)
void resolve_fallback(const float* __restrict__ z, const float* __restrict__ key,
                      const float* __restrict__ esq, const float* __restrict__ zsq,
                      const u64* __restrict__ cand, const int* __restrict__ cnt,
                      float* __restrict__ out, int* __restrict__ idxw)
{
    const int p   = blockIdx.x * 256 + threadIdx.x;
    const int b   = (p >= NLOC) ? 1 : 0;
    const int loc = p - b * NLOC;
    const float* zb = z + (size_t)b * Cc * NLOC;

    const int c = cnt[p];
    const int n = (c < SLOTS) ? c : SLOTS;
    u64 best = 0xFFFFFFFFFFFFFFFFull;
    for (int s = 0; s < n; ++s) {
        u64 v = cand[(size_t)p * SLOTS + s];
        if (v < best) best = v;
    }
    int kbest = (int)(u32)best;
    const float db = __uint_as_float((u32)(best >> 32));

    if (c > SLOTS) {
        u64 bb = 0xFFFFFFFFFFFFFFFFull;
        for (int k = 0; k < Kc; ++k) {
            const float* kr = key + (size_t)k * Cc;
            float m = 0.f;
            for (int cc = 0; cc < Cc; ++cc)
                m = fmaf(zb[(size_t)cc * NLOC + loc], kr[cc], m);
            float d = fmaf(-2.0f, m, zsq[p] + esq[k]);
            u64 pk = ((u64)__float_as_uint(d) << 32) | (u32)k;
            if (pk < bb) bb = pk;
        }
        kbest = (int)(u32)bb;
    } else {
        int namb = 0;
        for (int s = 0; s < n; ++s) {
            float dv = __uint_as_float((u32)(cand[(size_t)p * SLOTS + s] >> 32));
            namb += (dv <= db + WIN) ? 1 : 0;
        }
        if (namb > 1) {
            u64 bb = 0xFFFFFFFFFFFFFFFFull;
            for (int s = 0; s < n; ++s) {
                u64 v = cand[(size_t)p * SLOTS + s];
                float dv = __uint_as_float((u32)(v >> 32));
                if (dv <= db + WIN) {
                    int k = (int)(u32)v;
                    const float* kr = key + (size_t)k * Cc;
                    float m = 0.f;
                    for (int cc = 0; cc < Cc; ++cc)
                        m = fmaf(zb[(size_t)cc * NLOC + loc], kr[cc], m);
                    float d = fmaf(-2.0f, m, zsq[p] + esq[k]);
                    u64 pk = ((u64)__float_as_uint(d) << 32) | (u32)k;
                    if (pk < bb) bb = pk;
                }
            }
            kbest = (int)(u32)bb;
        }
    }
    idxw[p] = kbest;
    out[ZQV + p] = (float)kbest;
}

// ---------------------------------------------------------------------------
// gather: 32 rows/block; wave-distinct cc ranges (R12-validated).
// ---------------------------------------------------------------------------
__global__ __launch_bounds__(256)
void gather(const float* __restrict__ z, const float* __restrict__ key,
            const float* __restrict__ val, const int* __restrict__ idxw,
            float* __restrict__ out, double* __restrict__ partial)
{
    __shared__ float rowbuf[RB][261];
    __shared__ int   idx_sh[RB];
    __shared__ double wred[4];
    const int tid = threadIdx.x, blk = blockIdx.x;
    const int wid = tid >> 6, l = tid & 63;
    const int p0  = blk * RB;
    const int b   = (p0 >= NLOC) ? 1 : 0;
    const int loc0 = p0 - b * NLOC;
    const float* zb = z + (size_t)b * Cc * NLOC;

    if (tid < RB) idx_sh[tid] = idxw[p0 + tid];
    __syncthreads();

    #pragma unroll
    for (int i = 0; i < RB / 4; ++i) {
        int row = wid * (RB / 4) + i;
        float4 v = *reinterpret_cast<const float4*>(val + (size_t)idx_sh[row] * Cc + l * 4);
        *reinterpret_cast<float4*>(&rowbuf[row][l * 4]) = v;
    }
    __syncthreads();

    const int nq = l & 7;
    #pragma unroll
    for (int it = 0; it < 8; ++it) {
        int cc = (l >> 3) + 8 * it + 64 * wid;
        float4 v = make_float4(rowbuf[nq * 4 + 0][cc], rowbuf[nq * 4 + 1][cc],
                               rowbuf[nq * 4 + 2][cc], rowbuf[nq * 4 + 3][cc]);
        *reinterpret_cast<float4*>(
            out + ((size_t)b * Cc + cc) * NLOC + loc0 + nq * 4) = v;
    }
    __syncthreads();

    #pragma unroll
    for (int i = 0; i < RB / 4; ++i) {
        int row = wid * (RB / 4) + i;
        float4 v = *reinterpret_cast<const float4*>(key + (size_t)idx_sh[row] * Cc + l * 4);
        *reinterpret_cast<float4*>(&rowbuf[row][l * 4]) = v;
    }
    __syncthreads();

    double lacc = 0.0;
    #pragma unroll
    for (int it = 0; it < 8; ++it) {
        int cc = (l >> 3) + 8 * it + 64 * wid;
        float4 zv = *reinterpret_cast<const float4*>(
            zb + (size_t)cc * NLOC + loc0 + nq * 4);
        double d0 = (double)rowbuf[nq * 4 + 0][cc] - (double)zv.x;
        double d1 = (double)rowbuf[nq * 4 + 1][cc] - (double)zv.y;
        double d2 = (double)rowbuf[nq * 4 + 2][cc] - (double)zv.z;
        double d3 = (double)rowbuf[nq * 4 + 3][cc] - (double)zv.w;
        lacc = fma(d0, d0, lacc); lacc = fma(d1, d1, lacc);
        lacc = fma(d2, d2, lacc); lacc = fma(d3, d3, lacc);
    }
    for (int off = 32; off > 0; off >>= 1) lacc += __shfl_down(lacc, off);
    if (l == 0) wred[wid] = lacc;
    __syncthreads();
    if (tid == 0) partial[blk] = wred[0] + wred[1] + wred[2] + wred[3];
}

__global__ void fin_kernel(const double* __restrict__ partial, float* __restrict__ out_loss)
{
    __shared__ double sh[256];
    double s = 0.0;
    for (int i = threadIdx.x; i < F2B; i += 256) s += partial[i];
    sh[threadIdx.x] = s;
    __syncthreads();
    for (int st = 128; st > 0; st >>= 1) {
        if (threadIdx.x < st) sh[threadIdx.x] += sh[threadIdx.x + st];
        __syncthreads();
    }
    if (threadIdx.x == 0)
        out_loss[0] = (float)(1.25 * sh[0] / (double)((long long)NTOT * Cc));
}

// ---------------------------------------------------------------------------
extern "C" void kernel_launch(void* const* d_in, const int* in_sizes, int n_in,
                              void* d_out, int out_size, void* d_ws, size_t ws_size,
                              hipStream_t stream)
{
    const float* z   = (const float*)d_in[0];
    const float* key = (const float*)d_in[1];
    const float* val = (const float*)d_in[2];
    float* out = (float*)d_out;

    // zf16 scratch lives in the z_q_value output region (dead before gather)
    u16* zf16 = (u16*)d_out;

    char* w = (char*)d_ws;
    u16*    ef16    = (u16*)w;                 w += (size_t)Kc * Cc * 2;        // 512 KB
    u64*    cand    = (u64*)w;                 w += (size_t)NTOT * SLOTS * 8;   // 12.85 MB
    int*    cnt     = (int*)w;                 w += (size_t)NTOT * 4;           // 401 KB
    int*    wcount  = (int*)w;                 w += 16;
    int*    idxw    = (int*)w;                 w += (size_t)NTOT * 4;
    int*    wl      = (int*)w;                 w += (size_t)NTOT * 4;
    double* partial = (double*)w;              w += (size_t)F2B * 8;
    float*  esq     = (float*)w;               w += (size_t)Kc * 4;
    float*  zsq     = (float*)w;               w += (size_t)NTOT * 4;
    float*  zt32    = (float*)w;
    size_t  need_big = (size_t)(w - (char*)d_ws) + (size_t)NTOT * Cc * 4;
    const bool big = ws_size >= need_big;

    hipMemsetAsync(cnt, 0, (size_t)NTOT * 4 + 16, stream);  // cnt + wcount
    hipLaunchKernelGGL(esq_pw, dim3((Kc + 255) / 256), dim3(256), 0, stream, key, esq);
    hipLaunchKernelGGL(split_e, dim3((Kc * Cc + 255) / 256), dim3(256), 0, stream, key, ef16);
    hipLaunchKernelGGL(split_z, dim3(NTOT / 64), dim3(256), 0, stream, z, zf16,
                       big ? zt32 : (float*)nullptr, zsq);
    hipLaunchKernelGGL(screen, dim3(SBLK), dim3(256), 0, stream,
                       zf16, ef16, esq, zsq, cand, cnt);
    if (big) {
        hipLaunchKernelGGL(resolve_pick, dim3(F1B), dim3(256), 0, stream,
                           cand, cnt, idxw, out, wl, wcount);
        hipLaunchKernelGGL(rescore, dim3(F1B), dim3(256), 0, stream,
                           zt32, key, esq, zsq, cand, cnt, wcount, wl, idxw, out);
    } else {
        hipLaunchKernelGGL(resolve_fallback, dim3(F1B), dim3(256), 0, stream,
                           z, key, esq, zsq, cand, cnt, out, idxw);
    }
    hipLaunchKernelGGL(gather, dim3(F2B), dim3(256), 0, stream,
                       z, key, val, idxw, out, partial);
    hipLaunchKernelGGL(fin_kernel, dim3(1), dim3(256), 0, stream, partial, out + ZQV + NTOT);
}

// Round 14
// 394.992 us; speedup vs baseline: 2.5408x; 1.2247x over previous
//
#include <hip/hip_runtime.h>
#include <stdint.h>

constexpr int Cc   = 256;
constexpr int Kc   = 1024;
constexpr int NLOC = 16 * 56 * 56;      // 50176
constexpr int NB   = 2;
constexpr int NTOT = NB * NLOC;         // 100352
constexpr long long ZQV = (long long)NB * Cc * NLOC;  // 25690112

// screen tiling: one block = 128 rows x 128 codes, K=256 in 4 chunks of 64
constexpr int SR   = 128;
constexpr int SC   = 128;
constexpr int BK   = 64;
constexpr int NCH  = Cc / BK;           // 4
constexpr int NRT  = NTOT / SR;         // 784 row tiles (= 8 XCDs x 98)
constexpr int NSL  = Kc / SC;           // 8
constexpr int SBLK = NRT * NSL;         // 6272

constexpr int   SLOTS = 16;
constexpr float WIN   = 3e-4f;          // validated (absmax idx = 0 at 3e-4)
constexpr float NEG2S = -0.001953125f;  // -2/1024 (exact descale)

constexpr int F1B = NTOT / 256;         // 392
constexpr int RB  = 32;                 // rows per gather block
constexpr int F2B = NTOT / RB;          // 3136

using f16x8 = __attribute__((ext_vector_type(8))) _Float16;
using f32x4 = __attribute__((ext_vector_type(4))) float;
typedef unsigned long long u64;
typedef unsigned int       u32;
typedef unsigned short     u16;

// ---------------------------------------------------------------------------
// numpy-exact helpers (validated, unchanged)
// ---------------------------------------------------------------------------
__device__ __forceinline__ float sqf(float x) {
    float s = x * x;
    asm("" : "+v"(s));
    return s;
}

template <typename Loader>
__device__ __forceinline__ float pw256_sq(Loader ld)
{
    float half[2];
    #pragma unroll
    for (int h = 0; h < 2; ++h) {
        float r[8];
        #pragma unroll
        for (int j = 0; j < 8; ++j) r[j] = sqf(ld(h * 128 + j));
        #pragma unroll
        for (int i = 8; i < 128; i += 8)
            #pragma unroll
            for (int j = 0; j < 8; ++j) r[j] += sqf(ld(h * 128 + i + j));
        half[h] = ((r[0] + r[1]) + (r[2] + r[3])) + ((r[4] + r[5]) + (r[6] + r[7]));
    }
    return half[0] + half[1];
}

__global__ void esq_pw(const float* __restrict__ key, float* __restrict__ esq)
{
    int k = blockIdx.x * 256 + threadIdx.x;
    if (k < Kc) {
        const float* a = key + (size_t)k * Cc;
        esq[k] = pw256_sq([&](int c) { return a[c]; });
    }
}

__device__ __forceinline__ u16 f16b(float x)
{
    _Float16 h = (_Float16)x;   // v_cvt_f16_f32, RNE
    u16 r;
    __builtin_memcpy(&r, &h, 2);
    return r;
}

// split_e: ef16[k][c] = f16(key[k][c] * 1024)  (exact pow-2 scale)
__global__ void split_e(const float* __restrict__ key, u16* __restrict__ ef16)
{
    int i = blockIdx.x * 256 + threadIdx.x;
    if (i < Kc * Cc) ef16[i] = f16b(key[i] * 1024.0f);
}

// split_z: z [B][C][NLOC] f32 -> zf16 [NTOT][C] f16 (+ zt32 f32 copy, + zsq)
// zsq fused: rows sit in LDS; numpy-pairwise sum over bit-exact copies.
__global__ __launch_bounds__(256, 2)
void split_z(const float* __restrict__ z, u16* __restrict__ zf16,
             float* __restrict__ zt32, float* __restrict__ zsq)
{
    __shared__ float t[64][260];
    const int tid = threadIdx.x;
    const int n0  = blockIdx.x * 64;
    const int b   = (n0 >= NLOC) ? 1 : 0;
    const int loc0 = n0 - b * NLOC;
    const float* zb = z + (size_t)b * Cc * NLOC;

    {
        const int n4 = tid & 15;
        #pragma unroll
        for (int it = 0; it < 4; ++it) {
            int c4 = (tid >> 4) + it * 16;
            float4 g0 = *reinterpret_cast<const float4*>(zb + (size_t)(c4 * 4 + 0) * NLOC + loc0 + n4 * 4);
            float4 g1 = *reinterpret_cast<const float4*>(zb + (size_t)(c4 * 4 + 1) * NLOC + loc0 + n4 * 4);
            float4 g2 = *reinterpret_cast<const float4*>(zb + (size_t)(c4 * 4 + 2) * NLOC + loc0 + n4 * 4);
            float4 g3 = *reinterpret_cast<const float4*>(zb + (size_t)(c4 * 4 + 3) * NLOC + loc0 + n4 * 4);
            *reinterpret_cast<float4*>(&t[n4 * 4 + 0][c4 * 4]) = make_float4(g0.x, g1.x, g2.x, g3.x);
            *reinterpret_cast<float4*>(&t[n4 * 4 + 1][c4 * 4]) = make_float4(g0.y, g1.y, g2.y, g3.y);
            *reinterpret_cast<float4*>(&t[n4 * 4 + 2][c4 * 4]) = make_float4(g0.z, g1.z, g2.z, g3.z);
            *reinterpret_cast<float4*>(&t[n4 * 4 + 3][c4 * 4]) = make_float4(g0.w, g1.w, g2.w, g3.w);
        }
    }
    __syncthreads();
    {
        const int row2 = tid >> 5;
        const int ch   = tid & 31;
        #pragma unroll
        for (int rg = 0; rg < 8; ++rg) {
            int row = rg * 8 + row2;
            float4 f0 = *reinterpret_cast<const float4*>(&t[row][ch * 8]);
            float4 f1 = *reinterpret_cast<const float4*>(&t[row][ch * 8 + 4]);
            float xs[8] = {f0.x, f0.y, f0.z, f0.w, f1.x, f1.y, f1.z, f1.w};
            u32 hp[4];
            #pragma unroll
            for (int j = 0; j < 4; ++j)
                hp[j] = (u32)f16b(xs[2 * j]) | ((u32)f16b(xs[2 * j + 1]) << 16);
            size_t o = ((size_t)(n0 + row)) * Cc + ch * 8;
            *reinterpret_cast<uint4*>(zf16 + o) = make_uint4(hp[0], hp[1], hp[2], hp[3]);
            if (zt32) {
                *reinterpret_cast<float4*>(zt32 + o)     = f0;   // bit-exact f32 copies
                *reinterpret_cast<float4*>(zt32 + o + 4) = f1;
            }
        }
    }
    // fused zsq: numpy-pairwise over the LDS row (bit-exact copies)
    if (tid < 64)
        zsq[n0 + tid] = pw256_sq([&](int c) { return t[tid][c]; });
}

// global -> LDS direct, 16B/lane (dest = uniform base + lane*16)
__device__ __forceinline__ void gload16(const u16* g, u16* lds)
{
    __builtin_amdgcn_global_load_lds(
        (const __attribute__((address_space(1))) u32*)g,
        (__attribute__((address_space(3))) u32*)lds, 16, 0, 0);
}

// ---------------------------------------------------------------------------
// screen: f16 MFMA GEMM, 128x128 tile, BK=64, XCD-aware block remap.
// REVERTED to R12 single-buffered structure (R13's 2-phase dbuf regressed:
// 66KB LDS halved blocks/CU 4->2 while __syncthreads still drains vmcnt(0)).
// Keeps R13's f32 slice-min epilogue (strictly less VALU than u64 version).
// ---------------------------------------------------------------------------
__global__ __launch_bounds__(256, 4)
void screen(const u16* __restrict__ zf16, const u16* __restrict__ ef16,
            const float* __restrict__ esq, const float* __restrict__ zsq,
            u64* __restrict__ cand, int* __restrict__ cnt)
{
    __shared__ u16  A_lds[SR * BK];    // 16 KB
    __shared__ u16  B_lds[SC * BK];    // 16 KB
    __shared__ float gm[2][SR];        // 1 KB (f32 slice-min)
    __shared__ float esq_s[SC];
    __shared__ float zsq_s[SR];

    const int tid = threadIdx.x;
    const int bid = blockIdx.x;
    // XCD grouping: xcd = bid&7 owns row-tiles [xcd*98, (xcd+1)*98)
    const int q   = bid >> 3;
    const int rt  = (bid & 7) * (NRT / 8) + (q >> 3);
    const int r0  = rt * SR;
    const int k0  = (q & 7) * SC;
    const int wid = tid >> 6, l = tid & 63;
    const int wr  = wid >> 1, wc = wid & 1;

    for (int i = tid; i < SC; i += 256) esq_s[i] = esq[k0 + i];
    for (int i = tid; i < SR; i += 256) zsq_s[i] = zsq[r0 + i];

    f32x4 acc[4][4];
    #pragma unroll
    for (int i = 0; i < 4; ++i)
        #pragma unroll
        for (int j = 0; j < 4; ++j)
            acc[i][j] = f32x4{0.f, 0.f, 0.f, 0.f};

    for (int ch = 0; ch < NCH; ++ch) {
        __syncthreads();   // previous chunk consumed (covers esq_s/zsq_s on ch=0)
        {
            const int lr = l >> 3;
            #pragma unroll
            for (int t = 0; t < 4; ++t) {
                int rowb = wid * 32 + t * 8;
                int row  = rowb + lr;
                int g    = (l & 7) ^ (row & 7);
                gload16(zf16 + (size_t)(r0 + row) * Cc + ch * BK + g * 8,
                        A_lds + rowb * BK);
                gload16(ef16 + (size_t)(k0 + row) * Cc + ch * BK + g * 8,
                        B_lds + rowb * BK);
            }
        }
        __syncthreads();   // vmcnt drained

        #pragma unroll
        for (int kk = 0; kk < 2; ++kk) {
            f16x8 af[4], bf[4];
            const int G = kk * 4 + (l >> 4);
            #pragma unroll
            for (int i = 0; i < 4; ++i) {
                int row = wr * 64 + i * 16 + (l & 15);
                int pg  = G ^ (row & 7);
                af[i] = *reinterpret_cast<const f16x8*>(&A_lds[row * BK + pg * 8]);
            }
            #pragma unroll
            for (int j = 0; j < 4; ++j) {
                int col = wc * 64 + j * 16 + (l & 15);
                int pg  = G ^ (col & 7);
                bf[j] = *reinterpret_cast<const f16x8*>(&B_lds[col * BK + pg * 8]);
            }
            #pragma unroll
            for (int i = 0; i < 4; ++i)
                #pragma unroll
                for (int j = 0; j < 4; ++j)
                    acc[i][j] = __builtin_amdgcn_mfma_f32_16x16x32_f16(
                        af[i], bf[j], acc[i][j], 0, 0, 0);
        }
    }

    // ---- epilogue pass 1: f32 slice-min per row ----
    #pragma unroll
    for (int i = 0; i < 4; ++i) {
        #pragma unroll
        for (int r = 0; r < 4; ++r) {
            int rloc = wr * 64 + i * 16 + ((l >> 4) << 2) + r;
            float zq = zsq_s[rloc];
            float mn = 3.4e38f;
            #pragma unroll
            for (int j = 0; j < 4; ++j) {
                int cl = wc * 64 + j * 16 + (l & 15);
                float d = fmaf(NEG2S, acc[i][j][r], zq + esq_s[cl]);
                mn = fminf(mn, d);
            }
            #pragma unroll
            for (int m = 1; m < 16; m <<= 1)
                mn = fminf(mn, __shfl_xor(mn, m, 64));
            if ((l & 15) == 0) gm[wc][rloc] = mn;
        }
    }
    __syncthreads();

    // ---- epilogue pass 2: window emission ----
    #pragma unroll
    for (int i = 0; i < 4; ++i) {
        #pragma unroll
        for (int r = 0; r < 4; ++r) {
            int rloc = wr * 64 + i * 16 + ((l >> 4) << 2) + r;
            float thr = fminf(gm[0][rloc], gm[1][rloc]) + WIN;
            float zq = zsq_s[rloc];
            int rg = r0 + rloc;
            #pragma unroll
            for (int j = 0; j < 4; ++j) {
                int cl = wc * 64 + j * 16 + (l & 15);
                float d = fmaf(NEG2S, acc[i][j][r], zq + esq_s[cl]);
                if (d <= thr) {
                    int slot = atomicAdd(&cnt[rg], 1);
                    if (slot < SLOTS)
                        cand[(size_t)rg * SLOTS + slot] =
                            ((u64)__float_as_uint(d) << 32) | (u32)(k0 + cl);
                }
            }
        }
    }
}

// ---------------------------------------------------------------------------
// resolve_pick: thread per row; pick best candidate; push ambiguous/overflow
// rows to a worklist (no z reads here).
// ---------------------------------------------------------------------------
__global__ __launch_bounds__(256)
void resolve_pick(const u64* __restrict__ cand, const int* __restrict__ cnt,
                  int* __restrict__ idxw, float* __restrict__ out,
                  int* __restrict__ wl, int* __restrict__ wcount)
{
    const int p = blockIdx.x * 256 + threadIdx.x;
    const int c = cnt[p];
    const int n = (c < SLOTS) ? c : SLOTS;
    u64 best = 0xFFFFFFFFFFFFFFFFull;
    for (int s = 0; s < n; ++s) {
        u64 v = cand[(size_t)p * SLOTS + s];
        if (v < best) best = v;
    }
    const float db = __uint_as_float((u32)(best >> 32));

    bool needs = (c > SLOTS);
    if (!needs) {
        int namb = 0;
        for (int s = 0; s < n; ++s) {
            float dv = __uint_as_float((u32)(cand[(size_t)p * SLOTS + s] >> 32));
            namb += (dv <= db + WIN) ? 1 : 0;
        }
        needs = (namb > 1);
    }
    if (needs) wl[atomicAdd(wcount, 1)] = p;

    idxw[p] = (int)(u32)best;          // final for unambiguous rows
    out[ZQV + p] = (float)(u32)best;
}

// ---------------------------------------------------------------------------
// rescore: np-exact re-evaluation of worklist rows using contiguous zt32 rows.
// ---------------------------------------------------------------------------
__global__ __launch_bounds__(256)
void rescore(const float* __restrict__ zt32, const float* __restrict__ key,
             const float* __restrict__ esq, const float* __restrict__ zsq,
             const u64* __restrict__ cand, const int* __restrict__ cnt,
             const int* __restrict__ wcount, const int* __restrict__ wl,
             int* __restrict__ idxw, float* __restrict__ out)
{
    const int i = blockIdx.x * 256 + threadIdx.x;
    if (i >= *wcount) return;
    const int p = wl[i];
    const float* zr = zt32 + (size_t)p * Cc;   // bit-exact f32 z row
    const float zq = zsq[p];
    const int c = cnt[p];
    u64 bb = 0xFFFFFFFFFFFFFFFFull;

    if (c > SLOTS) {
        // overflow backstop: full np-exact scan
        for (int k = 0; k < Kc; ++k) {
            const float* kr = key + (size_t)k * Cc;
            float m = 0.f;
            for (int cc = 0; cc < Cc; ++cc)
                m = fmaf(zr[cc], kr[cc], m);
            float d = fmaf(-2.0f, m, zq + esq[k]);
            u64 pk = ((u64)__float_as_uint(d) << 32) | (u32)k;
            if (pk < bb) bb = pk;
        }
    } else {
        u64 best = 0xFFFFFFFFFFFFFFFFull;
        for (int s = 0; s < c; ++s) {
            u64 v = cand[(size_t)p * SLOTS + s];
            if (v < best) best = v;
        }
        const float db = __uint_as_float((u32)(best >> 32));
        for (int s = 0; s < c; ++s) {
            u64 v = cand[(size_t)p * SLOTS + s];
            float dv = __uint_as_float((u32)(v >> 32));
            if (dv <= db + WIN) {
                int k = (int)(u32)v;
                const float* kr = key + (size_t)k * Cc;
                float m = 0.f;
                for (int cc = 0; cc < Cc; ++cc)
                    m = fmaf(zr[cc], kr[cc], m);
                float d = fmaf(-2.0f, m, zq + esq[k]);
                u64 pk = ((u64)__float_as_uint(d) << 32) | (u32)k;
                if (pk < bb) bb = pk;
            }
        }
    }
    idxw[p] = (int)(u32)bb;
    out[ZQV + p] = (float)(u32)bb;
}

// ---------------------------------------------------------------------------
// resolve_fallback: monolithic path (strided z reads) if ws too small for zt32
// ---------------------------------------------------------------------------
__global__ __launch_bounds__(256)
void resolve_fallback(const float* __restrict__ z, const float* __restrict__ key,
                      const float* __restrict__ esq, const float* __restrict__ zsq,
                      const u64* __restrict__ cand, const int* __restrict__ cnt,
                      float* __restrict__ out, int* __restrict__ idxw)
{
    const int p   = blockIdx.x * 256 + threadIdx.x;
    const int b   = (p >= NLOC) ? 1 : 0;
    const int loc = p - b * NLOC;
    const float* zb = z + (size_t)b * Cc * NLOC;

    const int c = cnt[p];
    const int n = (c < SLOTS) ? c : SLOTS;
    u64 best = 0xFFFFFFFFFFFFFFFFull;
    for (int s = 0; s < n; ++s) {
        u64 v = cand[(size_t)p * SLOTS + s];
        if (v < best) best = v;
    }
    int kbest = (int)(u32)best;
    const float db = __uint_as_float((u32)(best >> 32));

    if (c > SLOTS) {
        u64 bb = 0xFFFFFFFFFFFFFFFFull;
        for (int k = 0; k < Kc; ++k) {
            const float* kr = key + (size_t)k * Cc;
            float m = 0.f;
            for (int cc = 0; cc < Cc; ++cc)
                m = fmaf(zb[(size_t)cc * NLOC + loc], kr[cc], m);
            float d = fmaf(-2.0f, m, zsq[p] + esq[k]);
            u64 pk = ((u64)__float_as_uint(d) << 32) | (u32)k;
            if (pk < bb) bb = pk;
        }
        kbest = (int)(u32)bb;
    } else {
        int namb = 0;
        for (int s = 0; s < n; ++s) {
            float dv = __uint_as_float((u32)(cand[(size_t)p * SLOTS + s] >> 32));
            namb += (dv <= db + WIN) ? 1 : 0;
        }
        if (namb > 1) {
            u64 bb = 0xFFFFFFFFFFFFFFFFull;
            for (int s = 0; s < n; ++s) {
                u64 v = cand[(size_t)p * SLOTS + s];
                float dv = __uint_as_float((u32)(v >> 32));
                if (dv <= db + WIN) {
                    int k = (int)(u32)v;
                    const float* kr = key + (size_t)k * Cc;
                    float m = 0.f;
                    for (int cc = 0; cc < Cc; ++cc)
                        m = fmaf(zb[(size_t)cc * NLOC + loc], kr[cc], m);
                    float d = fmaf(-2.0f, m, zsq[p] + esq[k]);
                    u64 pk = ((u64)__float_as_uint(d) << 32) | (u32)k;
                    if (pk < bb) bb = pk;
                }
            }
            kbest = (int)(u32)bb;
        }
    }
    idxw[p] = kbest;
    out[ZQV + p] = (float)kbest;
}

// ---------------------------------------------------------------------------
// gather: 32 rows/block; wave-distinct cc ranges (R12-validated).
// ---------------------------------------------------------------------------
__global__ __launch_bounds__(256)
void gather(const float* __restrict__ z, const float* __restrict__ key,
            const float* __restrict__ val, const int* __restrict__ idxw,
            float* __restrict__ out, double* __restrict__ partial)
{
    __shared__ float rowbuf[RB][261];
    __shared__ int   idx_sh[RB];
    __shared__ double wred[4];
    const int tid = threadIdx.x, blk = blockIdx.x;
    const int wid = tid >> 6, l = tid & 63;
    const int p0  = blk * RB;
    const int b   = (p0 >= NLOC) ? 1 : 0;
    const int loc0 = p0 - b * NLOC;
    const float* zb = z + (size_t)b * Cc * NLOC;

    if (tid < RB) idx_sh[tid] = idxw[p0 + tid];
    __syncthreads();

    #pragma unroll
    for (int i = 0; i < RB / 4; ++i) {
        int row = wid * (RB / 4) + i;
        float4 v = *reinterpret_cast<const float4*>(val + (size_t)idx_sh[row] * Cc + l * 4);
        *reinterpret_cast<float4*>(&rowbuf[row][l * 4]) = v;
    }
    __syncthreads();

    const int nq = l & 7;
    #pragma unroll
    for (int it = 0; it < 8; ++it) {
        int cc = (l >> 3) + 8 * it + 64 * wid;
        float4 v = make_float4(rowbuf[nq * 4 + 0][cc], rowbuf[nq * 4 + 1][cc],
                               rowbuf[nq * 4 + 2][cc], rowbuf[nq * 4 + 3][cc]);
        *reinterpret_cast<float4*>(
            out + ((size_t)b * Cc + cc) * NLOC + loc0 + nq * 4) = v;
    }
    __syncthreads();

    #pragma unroll
    for (int i = 0; i < RB / 4; ++i) {
        int row = wid * (RB / 4) + i;
        float4 v = *reinterpret_cast<const float4*>(key + (size_t)idx_sh[row] * Cc + l * 4);
        *reinterpret_cast<float4*>(&rowbuf[row][l * 4]) = v;
    }
    __syncthreads();

    double lacc = 0.0;
    #pragma unroll
    for (int it = 0; it < 8; ++it) {
        int cc = (l >> 3) + 8 * it + 64 * wid;
        float4 zv = *reinterpret_cast<const float4*>(
            zb + (size_t)cc * NLOC + loc0 + nq * 4);
        double d0 = (double)rowbuf[nq * 4 + 0][cc] - (double)zv.x;
        double d1 = (double)rowbuf[nq * 4 + 1][cc] - (double)zv.y;
        double d2 = (double)rowbuf[nq * 4 + 2][cc] - (double)zv.z;
        double d3 = (double)rowbuf[nq * 4 + 3][cc] - (double)zv.w;
        lacc = fma(d0, d0, lacc); lacc = fma(d1, d1, lacc);
        lacc = fma(d2, d2, lacc); lacc = fma(d3, d3, lacc);
    }
    for (int off = 32; off > 0; off >>= 1) lacc += __shfl_down(lacc, off);
    if (l == 0) wred[wid] = lacc;
    __syncthreads();
    if (tid == 0) partial[blk] = wred[0] + wred[1] + wred[2] + wred[3];
}

__global__ void fin_kernel(const double* __restrict__ partial, float* __restrict__ out_loss)
{
    __shared__ double sh[256];
    double s = 0.0;
    for (int i = threadIdx.x; i < F2B; i += 256) s += partial[i];
    sh[threadIdx.x] = s;
    __syncthreads();
    for (int st = 128; st > 0; st >>= 1) {
        if (threadIdx.x < st) sh[threadIdx.x] += sh[threadIdx.x + st];
        __syncthreads();
    }
    if (threadIdx.x == 0)
        out_loss[0] = (float)(1.25 * sh[0] / (double)((long long)NTOT * Cc));
}

// ---------------------------------------------------------------------------
extern "C" void kernel_launch(void* const* d_in, const int* in_sizes, int n_in,
                              void* d_out, int out_size, void* d_ws, size_t ws_size,
                              hipStream_t stream)
{
    const float* z   = (const float*)d_in[0];
    const float* key = (const float*)d_in[1];
    const float* val = (const float*)d_in[2];
    float* out = (float*)d_out;

    // zf16 scratch lives in the z_q_value output region (dead before gather)
    u16* zf16 = (u16*)d_out;

    char* w = (char*)d_ws;
    u16*    ef16    = (u16*)w;                 w += (size_t)Kc * Cc * 2;        // 512 KB
    u64*    cand    = (u64*)w;                 w += (size_t)NTOT * SLOTS * 8;   // 12.85 MB
    int*    cnt     = (int*)w;                 w += (size_t)NTOT * 4;           // 401 KB
    int*    wcount  = (int*)w;                 w += 16;
    int*    idxw    = (int*)w;                 w += (size_t)NTOT * 4;
    int*    wl      = (int*)w;                 w += (size_t)NTOT * 4;
    double* partial = (double*)w;              w += (size_t)F2B * 8;
    float*  esq     = (float*)w;               w += (size_t)Kc * 4;
    float*  zsq     = (float*)w;               w += (size_t)NTOT * 4;
    float*  zt32    = (float*)w;
    size_t  need_big = (size_t)(w - (char*)d_ws) + (size_t)NTOT * Cc * 4;
    const bool big = ws_size >= need_big;

    hipMemsetAsync(cnt, 0, (size_t)NTOT * 4 + 16, stream);  // cnt + wcount
    hipLaunchKernelGGL(esq_pw, dim3((Kc + 255) / 256), dim3(256), 0, stream, key, esq);
    hipLaunchKernelGGL(split_e, dim3((Kc * Cc + 255) / 256), dim3(256), 0, stream, key, ef16);
    hipLaunchKernelGGL(split_z, dim3(NTOT / 64), dim3(256), 0, stream, z, zf16,
                       big ? zt32 : (float*)nullptr, zsq);
    hipLaunchKernelGGL(screen, dim3(SBLK), dim3(256), 0, stream,
                       zf16, ef16, esq, zsq, cand, cnt);
    if (big) {
        hipLaunchKernelGGL(resolve_pick, dim3(F1B), dim3(256), 0, stream,
                           cand, cnt, idxw, out, wl, wcount);
        hipLaunchKernelGGL(rescore, dim3(F1B), dim3(256), 0, stream,
                           zt32, key, esq, zsq, cand, cnt, wcount, wl, idxw, out);
    } else {
        hipLaunchKernelGGL(resolve_fallback, dim3(F1B), dim3(256), 0, stream,
                           z, key, esq, zsq, cand, cnt, out, idxw);
    }
    hipLaunchKernelGGL(gather, dim3(F2B), dim3(256), 0, stream,
                       z, key, val, idxw, out, partial);
    hipLaunchKernelGGL(fin_kernel, dim3(1), dim3(256), 0, stream, partial, out + ZQV + NTOT);
}